// Round 1
// baseline (1414.698 us; speedup 1.0000x reference)
//
#include <hip/hip_runtime.h>

typedef unsigned short u16;
typedef __attribute__((ext_vector_type(8))) short bh8;   // 8 x bf16 bits (4 VGPRs)
typedef __attribute__((ext_vector_type(4))) float f4;    // MFMA accumulator

__device__ __forceinline__ float bf2f(u16 u) {
  union { unsigned int i; float f; } x; x.i = ((unsigned int)u) << 16; return x.f;
}
__device__ __forceinline__ u16 f2bf(float f) {
  union { float f; unsigned int i; } x; x.f = f;
  unsigned int r = x.i + 0x7fffu + ((x.i >> 16) & 1u);
  return (u16)(r >> 16);
}
__device__ __forceinline__ f4 mfma16(bh8 a, bh8 b, f4 c) {
  return __builtin_amdgcn_mfma_f32_16x16x32_bf16(a, b, c, 0, 0, 0);
}
__device__ __forceinline__ void gload16(const void* g, void* l) {
  __builtin_amdgcn_global_load_lds(
      (const __attribute__((address_space(1))) void*)g,
      (__attribute__((address_space(3))) void*)l, 16, 0, 0);
}
__device__ __forceinline__ void store_out(float* p, float v) { *p = v; }
__device__ __forceinline__ void store_out(u16* p, float v) { *p = f2bf(v); }

// ---------------- weight transpose: fp32 [R][C] -> bf16 [C][R] ----------------
__global__ __launch_bounds__(256)
void wtrans_k(const float* __restrict__ src, u16* __restrict__ dst, int R, int C) {
  __shared__ float tile[32][33];
  int tx = threadIdx.x & 31, ty = threadIdx.x >> 5;
  int c0 = blockIdx.x * 32, r0 = blockIdx.y * 32;
#pragma unroll
  for (int yy = 0; yy < 32; yy += 8)
    tile[ty + yy][tx] = src[(size_t)(r0 + ty + yy) * C + c0 + tx];
  __syncthreads();
#pragma unroll
  for (int yy = 0; yy < 32; yy += 8)
    dst[(size_t)(c0 + ty + yy) * R + r0 + tx] = f2bf(tile[tx][ty + yy]);
}

// ---------------- RMSNorm over D=2048, fp32 in -> bf16 out ----------------
__global__ __launch_bounds__(256)
void rmsnorm_k(const float* __restrict__ x, const float* __restrict__ w,
               u16* __restrict__ out) {
  int row = blockIdx.x, t = threadIdx.x;
  const float* xr = x + (size_t)row * 2048;
  float4 a = ((const float4*)xr)[t * 2];
  float4 b = ((const float4*)xr)[t * 2 + 1];
  float ss = a.x*a.x + a.y*a.y + a.z*a.z + a.w*a.w
           + b.x*b.x + b.y*b.y + b.z*b.z + b.w*b.w;
#pragma unroll
  for (int s = 32; s > 0; s >>= 1) ss += __shfl_xor(ss, s, 64);
  __shared__ float red[4];
  if ((t & 63) == 0) red[t >> 6] = ss;
  __syncthreads();
  float rr = rsqrtf((red[0] + red[1] + red[2] + red[3]) * (1.0f / 2048.0f) + 1e-6f);
  float v[8] = {a.x, a.y, a.z, a.w, b.x, b.y, b.z, b.w};
  int c0 = t * 8;
  u16* orow = out + (size_t)row * 2048 + c0;
#pragma unroll
  for (int j = 0; j < 8; ++j) orow[j] = f2bf(v[j] * rr * w[c0 + j]);
}

// ---------------- bf16 GEMM: C[M][N] = A[M][K] * Bt[N][K]^T  (m97 structure) ----------------
// EPI 0: C = acc*scale ; EPI 1: C = acc + auxF32[idx] ; EPI 2: C = silu(auxBf16[idx]) * acc
template <int EPI, typename OutT>
__global__ __launch_bounds__(256)
void gemm_bt(const u16* __restrict__ A, const u16* __restrict__ Bt,
             OutT* C, const void* aux, float scale, int M, int N, int K) {
  __shared__ u16 As[4096];  // [128][32]
  __shared__ u16 Bs[4096];
  int t = threadIdx.x, lane = t & 63, wave = t >> 6;
  int m0 = blockIdx.y * 128, n0 = blockIdx.x * 128;
  int wr = (wave >> 1) * 64, wc = (wave & 1) * 64;
  int c_ = lane & 15, r_ = lane >> 4;
  f4 z4 = {0.f, 0.f, 0.f, 0.f};
  f4 acc[4][4];
#pragma unroll
  for (int m = 0; m < 4; ++m)
#pragma unroll
    for (int n = 0; n < 4; ++n) acc[m][n] = z4;

  const u16* Ab = A + (size_t)m0 * K;
  const u16* Bb = Bt + (size_t)n0 * K;
  int srow = t >> 2, scol = (t & 3) * 8;
  char* AsB = (char*)As;
  char* BsB = (char*)Bs;
  int ldsbase = wave * 1024;  // wave-uniform, lane*16 added by HW

  for (int k0 = 0; k0 < K; k0 += 32) {
#pragma unroll
    for (int p = 0; p < 2; ++p) {
      gload16(Ab + (size_t)(p * 64 + srow) * K + k0 + scol, AsB + p * 4096 + ldsbase);
      gload16(Bb + (size_t)(p * 64 + srow) * K + k0 + scol, BsB + p * 4096 + ldsbase);
    }
    __syncthreads();
    bh8 af[4], bfr[4];
#pragma unroll
    for (int m = 0; m < 4; ++m) af[m] = *(const bh8*)&As[(wr + m * 16 + c_) * 32 + r_ * 8];
#pragma unroll
    for (int n = 0; n < 4; ++n) bfr[n] = *(const bh8*)&Bs[(wc + n * 16 + c_) * 32 + r_ * 8];
#pragma unroll
    for (int m = 0; m < 4; ++m)
#pragma unroll
      for (int n = 0; n < 4; ++n) acc[m][n] = mfma16(af[m], bfr[n], acc[m][n]);
    __syncthreads();
  }
#pragma unroll
  for (int m = 0; m < 4; ++m) {
#pragma unroll
    for (int r = 0; r < 4; ++r) {
      int rowg = m0 + wr + m * 16 + r_ * 4 + r;
      size_t rb = (size_t)rowg * N;
#pragma unroll
      for (int n = 0; n < 4; ++n) {
        size_t idx = rb + n0 + wc + n * 16 + c_;
        float val = acc[m][n][r];
        if (EPI == 0) val *= scale;
        else if (EPI == 1) val += ((const float*)aux)[idx];
        else if (EPI == 2) {
          float gv = bf2f(((const u16*)aux)[idx]);
          val = val * (gv / (1.f + expf(-gv)));
        }
        store_out(&C[idx], val);
      }
    }
  }
}

// ---------------- low-rank gate path: g = log_sigmoid(h@w1@w2 + b)/16 ----------------
__global__ __launch_bounds__(256)
void lowrank_k(const u16* __restrict__ h, const float* __restrict__ w1,
               const float* __restrict__ w2, const float* __restrict__ bias,
               float* __restrict__ g) {
  int row = blockIdx.x, t = threadIdx.x, lane = t & 63, wave = t >> 6;
  const u16* hr = h + (size_t)row * 2048;
  bh8 hv = *(const bh8*)&hr[t * 8];
  float p[16];
#pragma unroll
  for (int j = 0; j < 16; ++j) p[j] = 0.f;
#pragma unroll
  for (int kk = 0; kk < 8; ++kk) {
    float f = bf2f((u16)hv[kk]);
    const float* wrow = w1 + (size_t)(t * 8 + kk) * 16;
#pragma unroll
    for (int j = 0; j < 16; ++j) p[j] += f * wrow[j];
  }
#pragma unroll
  for (int j = 0; j < 16; ++j)
#pragma unroll
    for (int s = 32; s > 0; s >>= 1) p[j] += __shfl_xor(p[j], s, 64);
  __shared__ float gl[4][16];
  if (lane == 0) {
#pragma unroll
    for (int j = 0; j < 16; ++j) gl[wave][j] = p[j];
  }
  __syncthreads();
  float glow[16];
#pragma unroll
  for (int j = 0; j < 16; ++j) glow[j] = gl[0][j] + gl[1][j] + gl[2][j] + gl[3][j];
  float* grow = g + (size_t)row * 1024;
#pragma unroll
  for (int nn = 0; nn < 4; ++nn) {
    int n = nn * 256 + t;
    float z = bias[n];
#pragma unroll
    for (int j = 0; j < 16; ++j) z += glow[j] * w2[j * 1024 + n];
    float ls = fminf(z, 0.f) - log1pf(expf(-fabsf(z)));
    grow[n] = ls * (1.0f / 16.0f);
  }
}

// ---------------- GLA chunked scan ----------------
// grid = 64 : (b,h) x 4 HV-slices of 64. S kept fp32 master + bf16 shadow (S^T layout [v][k]).
__global__ __launch_bounds__(256)
void gla_scan(const u16* __restrict__ qg, const u16* __restrict__ kg,
              const u16* __restrict__ vg, const float* __restrict__ gg,
              float* __restrict__ outp) {
  __shared__ u16 S_bf[64][136];    // S^T bf16 shadow [v][kk]
  __shared__ float S_f[64][132];   // S^T fp32 master
  __shared__ u16 qe[64][136];      // [i][kk]  (q * e^b)
  __shared__ u16 ke[64][136];      // [i][kk]  (k * e^-b)
  __shared__ u16 kdT[128][72];     // [kk][i]  (k * e^(bl-b))
  __shared__ u16 vT[64][72];       // [v][i]
  __shared__ u16 Abf[64][72];      // [i][j] tril(qe ke^T)
  __shared__ float bl[128];
  __shared__ float ebl[128];

  int t = threadIdx.x, lane = t & 63, w = t >> 6;
  int vb = blockIdx.x & 3, bhh = blockIdx.x >> 2;
  int b = bhh >> 3, h = bhh & 7;
  int c_ = lane & 15, r_ = lane >> 4;
  size_t qkbase = (size_t)b * 2048 * 1024 + h * 128;
  size_t vbase = (size_t)b * 2048 * 2048 + h * 256 + vb * 64;
  f4 z4 = {0.f, 0.f, 0.f, 0.f};

  for (int idx = t; idx < 64 * 136; idx += 256) ((u16*)S_bf)[idx] = 0;
  for (int idx = t; idx < 64 * 132; idx += 256) ((float*)S_f)[idx] = 0.f;
  __syncthreads();

  for (int c = 0; c < 32; ++c) {
    int tok0 = c * 64;
    // stage q,k chunk (raw bf16)
#pragma unroll
    for (int it = 0; it < 4; ++it) {
      int flat = it * 256 + t;
      int i = flat >> 4, c8 = (flat & 15) * 8;
      *(bh8*)&qe[i][c8] = *(const bh8*)&qg[qkbase + (size_t)(tok0 + i) * 1024 + c8];
      *(bh8*)&ke[i][c8] = *(const bh8*)&kg[qkbase + (size_t)(tok0 + i) * 1024 + c8];
    }
    // stage v transposed
    {
      int i0 = t >> 3, v0 = (t & 7) * 8;
#pragma unroll
      for (int half = 0; half < 2; ++half) {
        int i = i0 + half * 32;
        bh8 vv = *(const bh8*)&vg[vbase + (size_t)(tok0 + i) * 2048 + v0];
#pragma unroll
        for (int j = 0; j < 8; ++j) vT[v0 + j][i] = (u16)vv[j];
      }
    }
    __syncthreads();
    // gating: cumsum along chunk per HK channel; build qe, ke, kdT in place
    if (t < 128) {
      int ch = t;
      const float* gc = gg + qkbase + (size_t)tok0 * 1024 + ch;
      float bacc = 0.f;
      for (int i = 0; i < 64; ++i) bacc += gc[(size_t)i * 1024];
      bl[ch] = bacc;
      float eblv = expf(bacc);
      ebl[ch] = eblv;
      bacc = 0.f;
      for (int i = 0; i < 64; ++i) {
        bacc += gc[(size_t)i * 1024];
        float eb = expf(bacc);
        float reb = __builtin_amdgcn_rcpf(eb);
        float qv = bf2f(qe[i][ch]);
        float kv = bf2f(ke[i][ch]);
        qe[i][ch] = f2bf(qv * eb);
        ke[i][ch] = f2bf(kv * reb);
        kdT[ch][i] = f2bf(kv * eblv * reb);
      }
    }
    __syncthreads();
    // A = tril(qe @ ke^T), K = HK = 128; wave w owns rows [w*16, w*16+16)
    {
      f4 accA[4];
#pragma unroll
      for (int n = 0; n < 4; ++n) accA[n] = z4;
#pragma unroll
      for (int ks = 0; ks < 4; ++ks) {
        bh8 a = *(const bh8*)&qe[w * 16 + c_][ks * 32 + r_ * 8];
#pragma unroll
        for (int n = 0; n < 4; ++n) {
          bh8 bb = *(const bh8*)&ke[n * 16 + c_][ks * 32 + r_ * 8];
          accA[n] = mfma16(a, bb, accA[n]);
        }
      }
#pragma unroll
      for (int n = 0; n < 4; ++n)
#pragma unroll
        for (int r = 0; r < 4; ++r) {
          int i = w * 16 + r_ * 4 + r, j = n * 16 + c_;
          Abf[i][j] = f2bf((j <= i) ? accA[n][r] : 0.f);
        }
    }
    __syncthreads();
    // o = qe@S + Abf@v ; S-delta = kdT@v ; then S update
    {
      f4 acco[4];
#pragma unroll
      for (int n = 0; n < 4; ++n) acco[n] = z4;
#pragma unroll
      for (int ks = 0; ks < 4; ++ks) {
        bh8 a = *(const bh8*)&qe[w * 16 + c_][ks * 32 + r_ * 8];
#pragma unroll
        for (int n = 0; n < 4; ++n) {
          bh8 s = *(const bh8*)&S_bf[n * 16 + c_][ks * 32 + r_ * 8];
          acco[n] = mfma16(a, s, acco[n]);
        }
      }
#pragma unroll
      for (int ks = 0; ks < 2; ++ks) {
        bh8 a = *(const bh8*)&Abf[w * 16 + c_][ks * 32 + r_ * 8];
#pragma unroll
        for (int n = 0; n < 4; ++n) {
          bh8 vv = *(const bh8*)&vT[n * 16 + c_][ks * 32 + r_ * 8];
          acco[n] = mfma16(a, vv, acco[n]);
        }
      }
#pragma unroll
      for (int n = 0; n < 4; ++n)
#pragma unroll
        for (int r = 0; r < 4; ++r)
          outp[(size_t)(b * 2048 + tok0 + w * 16 + r_ * 4 + r) * 2048 +
               h * 256 + vb * 64 + n * 16 + c_] = acco[n][r];

      f4 accS[2][4];
#pragma unroll
      for (int kt = 0; kt < 2; ++kt)
#pragma unroll
        for (int n = 0; n < 4; ++n) accS[kt][n] = z4;
#pragma unroll
      for (int ks = 0; ks < 2; ++ks) {
#pragma unroll
        for (int kt = 0; kt < 2; ++kt) {
          bh8 a = *(const bh8*)&kdT[w * 32 + kt * 16 + c_][ks * 32 + r_ * 8];
#pragma unroll
          for (int n = 0; n < 4; ++n) {
            bh8 vv = *(const bh8*)&vT[n * 16 + c_][ks * 32 + r_ * 8];
            accS[kt][n] = mfma16(a, vv, accS[kt][n]);
          }
        }
      }
      __syncthreads();  // all reads of S_bf/vT/kdT done
#pragma unroll
      for (int kt = 0; kt < 2; ++kt)
#pragma unroll
        for (int n = 0; n < 4; ++n)
#pragma unroll
          for (int r = 0; r < 4; ++r) {
            int kk = w * 32 + kt * 16 + r_ * 4 + r;
            int vcol = n * 16 + c_;
            float nv = ebl[kk] * S_f[vcol][kk] + accS[kt][n][r];
            S_f[vcol][kk] = nv;
            S_bf[vcol][kk] = f2bf(nv);
          }
      __syncthreads();
    }
  }
}

// ---------------- per-head RMSNorm * swish(gate) ----------------
__global__ __launch_bounds__(256)
void ogate_k(const float* __restrict__ o, const u16* __restrict__ gate,
             const float* __restrict__ gw, u16* __restrict__ og) {
  int tok = blockIdx.x, t = threadIdx.x;
  int head = t >> 5, l32 = t & 31, v0 = l32 * 8;
  size_t base = (size_t)tok * 2048 + head * 256 + v0;
  float4 a = *(const float4*)&o[base];
  float4 b = *(const float4*)&o[base + 4];
  float ov[8] = {a.x, a.y, a.z, a.w, b.x, b.y, b.z, b.w};
  float ss = 0.f;
#pragma unroll
  for (int j = 0; j < 8; ++j) ss += ov[j] * ov[j];
#pragma unroll
  for (int s = 16; s > 0; s >>= 1) ss += __shfl_xor(ss, s, 32);
  float rr = rsqrtf(ss * (1.0f / 256.0f) + 1e-6f);
#pragma unroll
  for (int j = 0; j < 8; ++j) {
    float gv = bf2f(gate[base + j]);
    float val = ov[j] * rr * gw[v0 + j];
    og[base + j] = f2bf(val * gv / (1.f + expf(-gv)));
  }
}

// ---------------- launch ----------------
extern "C" void kernel_launch(void* const* d_in, const int* in_sizes, int n_in,
                              void* d_out, int out_size, void* d_ws, size_t ws_size,
                              hipStream_t stream) {
  (void)in_sizes; (void)n_in; (void)out_size; (void)ws_size;
  const float* x = (const float*)d_in[0];
  const float* n1w = (const float*)d_in[1];
  const float* wq = (const float*)d_in[2];
  const float* wk = (const float*)d_in[3];
  const float* wv = (const float*)d_in[4];
  const float* gw1 = (const float*)d_in[5];
  const float* gw2 = (const float*)d_in[6];
  const float* gb = (const float*)d_in[7];
  const float* wg = (const float*)d_in[8];
  const float* gnw = (const float*)d_in[9];
  const float* wo = (const float*)d_in[10];
  const float* fnw = (const float*)d_in[11];
  const float* wgate = (const float*)d_in[12];
  const float* wup = (const float*)d_in[13];
  const float* wdown = (const float*)d_in[14];
  float* out = (float*)d_out;

  char* ws = (char*)d_ws;
  size_t off = 0;
  auto alloc = [&](size_t bytes) { size_t p = off; off += (bytes + 255) & ~(size_t)255; return p; };
  u16* wqT = (u16*)(ws + alloc(2ull * 1024 * 2048));
  u16* wkT = (u16*)(ws + alloc(2ull * 1024 * 2048));
  u16* wvT = (u16*)(ws + alloc(2ull * 2048 * 2048));
  u16* wgT = (u16*)(ws + alloc(2ull * 2048 * 2048));
  u16* woT = (u16*)(ws + alloc(2ull * 2048 * 2048));
  u16* wgateT = (u16*)(ws + alloc(2ull * 5504 * 2048));
  u16* wupT = (u16*)(ws + alloc(2ull * 5504 * 2048));
  u16* wdT = (u16*)(ws + alloc(2ull * 2048 * 5504));
  u16* h_bf = (u16*)(ws + alloc(2ull * 4096 * 2048));   // later reused as og
  u16* q_bf = (u16*)(ws + alloc(2ull * 4096 * 1024));   // later (with k_bf) reused as h2
  u16* k_bf = (u16*)(ws + alloc(2ull * 4096 * 1024));
  u16* v_bf = (u16*)(ws + alloc(2ull * 4096 * 2048));
  u16* gate_bf = (u16*)(ws + alloc(2ull * 4096 * 2048));
  float* g_f = (float*)(ws + alloc(4ull * 4096 * 1024));
  float* o_f = (float*)(ws + alloc(4ull * 4096 * 2048));  // later reused as x2
  u16* gH = (u16*)(ws + alloc(2ull * 4096 * 5504));       // later reused as mid
  u16* og = h_bf;
  u16* h2 = q_bf;
  float* x2 = o_f;
  u16* mid = gH;

  dim3 blk(256);
  wtrans_k<<<dim3(32, 64), blk, 0, stream>>>(wq, wqT, 2048, 1024);
  wtrans_k<<<dim3(32, 64), blk, 0, stream>>>(wk, wkT, 2048, 1024);
  wtrans_k<<<dim3(64, 64), blk, 0, stream>>>(wv, wvT, 2048, 2048);
  wtrans_k<<<dim3(64, 64), blk, 0, stream>>>(wg, wgT, 2048, 2048);
  wtrans_k<<<dim3(64, 64), blk, 0, stream>>>(wo, woT, 2048, 2048);
  wtrans_k<<<dim3(172, 64), blk, 0, stream>>>(wgate, wgateT, 2048, 5504);
  wtrans_k<<<dim3(172, 64), blk, 0, stream>>>(wup, wupT, 2048, 5504);
  wtrans_k<<<dim3(64, 172), blk, 0, stream>>>(wdown, wdT, 5504, 2048);

  rmsnorm_k<<<4096, blk, 0, stream>>>(x, n1w, h_bf);

  gemm_bt<0, u16><<<dim3(8, 32), blk, 0, stream>>>(h_bf, wqT, q_bf, nullptr, 0.08838834764831845f, 4096, 1024, 2048);
  gemm_bt<0, u16><<<dim3(8, 32), blk, 0, stream>>>(h_bf, wkT, k_bf, nullptr, 1.f, 4096, 1024, 2048);
  gemm_bt<0, u16><<<dim3(16, 32), blk, 0, stream>>>(h_bf, wvT, v_bf, nullptr, 1.f, 4096, 2048, 2048);
  gemm_bt<0, u16><<<dim3(16, 32), blk, 0, stream>>>(h_bf, wgT, gate_bf, nullptr, 1.f, 4096, 2048, 2048);
  lowrank_k<<<4096, blk, 0, stream>>>(h_bf, gw1, gw2, gb, g_f);

  gla_scan<<<64, blk, 0, stream>>>(q_bf, k_bf, v_bf, g_f, o_f);

  ogate_k<<<4096, blk, 0, stream>>>(o_f, gate_bf, gnw, og);

  gemm_bt<1, float><<<dim3(16, 32), blk, 0, stream>>>(og, woT, x2, x, 1.f, 4096, 2048, 2048);

  rmsnorm_k<<<4096, blk, 0, stream>>>(x2, fnw, h2);

  gemm_bt<0, u16><<<dim3(43, 32), blk, 0, stream>>>(h2, wgateT, gH, nullptr, 1.f, 4096, 5504, 2048);
  gemm_bt<2, u16><<<dim3(43, 32), blk, 0, stream>>>(h2, wupT, mid, gH, 1.f, 4096, 5504, 2048);
  gemm_bt<1, float><<<dim3(16, 32), blk, 0, stream>>>(mid, wdT, out, x2, 1.f, 4096, 2048, 5504);
}

// Round 2
// 1140.623 us; speedup vs baseline: 1.2403x; 1.2403x over previous
//
#include <hip/hip_runtime.h>

typedef unsigned short u16;
typedef __attribute__((ext_vector_type(8))) short bh8;   // 8 x bf16 bits (4 VGPRs)
typedef __attribute__((ext_vector_type(4))) float f4;    // MFMA accumulator

__device__ __forceinline__ float bf2f(u16 u) {
  union { unsigned int i; float f; } x; x.i = ((unsigned int)u) << 16; return x.f;
}
__device__ __forceinline__ u16 f2bf(float f) {
  union { float f; unsigned int i; } x; x.f = f;
  unsigned int r = x.i + 0x7fffu + ((x.i >> 16) & 1u);
  return (u16)(r >> 16);
}
__device__ __forceinline__ f4 mfma16(bh8 a, bh8 b, f4 c) {
  return __builtin_amdgcn_mfma_f32_16x16x32_bf16(a, b, c, 0, 0, 0);
}
__device__ __forceinline__ void gload16(const void* g, void* l) {
  __builtin_amdgcn_global_load_lds(
      (const __attribute__((address_space(1))) void*)g,
      (__attribute__((address_space(3))) void*)l, 16, 0, 0);
}
__device__ __forceinline__ void store_out(float* p, float v) { *p = v; }
__device__ __forceinline__ void store_out(u16* p, float v) { *p = f2bf(v); }

// swizzled LDS read: dense row-major array, byte-in-row XOR'd by (row&7)<<4
__device__ __forceinline__ bh8 rd8(const u16* arr, int row, int col, int rowbytes) {
  return *(const bh8*)((const char*)arr + row * rowbytes + ((col * 2) ^ ((row & 7) << 4)));
}

// ---------------- weight transpose: fp32 [R][C] -> bf16 [C][R] ----------------
__global__ __launch_bounds__(256)
void wtrans_k(const float* __restrict__ src, u16* __restrict__ dst, int R, int C) {
  __shared__ float tile[32][33];
  int tx = threadIdx.x & 31, ty = threadIdx.x >> 5;
  int c0 = blockIdx.x * 32, r0 = blockIdx.y * 32;
#pragma unroll
  for (int yy = 0; yy < 32; yy += 8)
    tile[ty + yy][tx] = src[(size_t)(r0 + ty + yy) * C + c0 + tx];
  __syncthreads();
#pragma unroll
  for (int yy = 0; yy < 32; yy += 8)
    dst[(size_t)(c0 + ty + yy) * R + r0 + tx] = f2bf(tile[tx][ty + yy]);
}

// ---------------- RMSNorm over D=2048, fp32 in -> bf16 out ----------------
__global__ __launch_bounds__(256)
void rmsnorm_k(const float* __restrict__ x, const float* __restrict__ w,
               u16* __restrict__ out) {
  int row = blockIdx.x, t = threadIdx.x;
  const float* xr = x + (size_t)row * 2048;
  float4 a = ((const float4*)xr)[t * 2];
  float4 b = ((const float4*)xr)[t * 2 + 1];
  float ss = a.x*a.x + a.y*a.y + a.z*a.z + a.w*a.w
           + b.x*b.x + b.y*b.y + b.z*b.z + b.w*b.w;
#pragma unroll
  for (int s = 32; s > 0; s >>= 1) ss += __shfl_xor(ss, s, 64);
  __shared__ float red[4];
  if ((t & 63) == 0) red[t >> 6] = ss;
  __syncthreads();
  float rr = rsqrtf((red[0] + red[1] + red[2] + red[3]) * (1.0f / 2048.0f) + 1e-6f);
  float v[8] = {a.x, a.y, a.z, a.w, b.x, b.y, b.z, b.w};
  int c0 = t * 8;
  u16* orow = out + (size_t)row * 2048 + c0;
#pragma unroll
  for (int j = 0; j < 8; ++j) orow[j] = f2bf(v[j] * rr * w[c0 + j]);
}

// ---------------- bf16 GEMM: C[M][N] = A[M][K] * Bt[N][K]^T  (m97 structure) ----------------
// EPI 0: C = acc*scale
// EPI 1: C = acc + auxF32[idx]
// EPI 2: C = silu(auxBf16[idx]) * acc
// EPI 3: write transposed+swizzled per-(b,chunk,head) panels for the GLA scan (v path)
template <int EPI, typename OutT>
__global__ __launch_bounds__(256)
void gemm_bt(const u16* __restrict__ A, const u16* __restrict__ Bt,
             OutT* C, const void* aux, float scale, int M, int N, int K) {
  __shared__ u16 As[4096];  // [128][32]
  __shared__ u16 Bs[4096];
  int t = threadIdx.x, lane = t & 63, wave = t >> 6;
  int m0 = blockIdx.y * 128, n0 = blockIdx.x * 128;
  int wr = (wave >> 1) * 64, wc = (wave & 1) * 64;
  int c_ = lane & 15, r_ = lane >> 4;
  f4 z4 = {0.f, 0.f, 0.f, 0.f};
  f4 acc[4][4];
#pragma unroll
  for (int m = 0; m < 4; ++m)
#pragma unroll
    for (int n = 0; n < 4; ++n) acc[m][n] = z4;

  const u16* Ab = A + (size_t)m0 * K;
  const u16* Bb = Bt + (size_t)n0 * K;
  int srow = t >> 2, scol = (t & 3) * 8;
  char* AsB = (char*)As;
  char* BsB = (char*)Bs;
  int ldsbase = wave * 1024;  // wave-uniform, lane*16 added by HW

  for (int k0 = 0; k0 < K; k0 += 32) {
#pragma unroll
    for (int p = 0; p < 2; ++p) {
      gload16(Ab + (size_t)(p * 64 + srow) * K + k0 + scol, AsB + p * 4096 + ldsbase);
      gload16(Bb + (size_t)(p * 64 + srow) * K + k0 + scol, BsB + p * 4096 + ldsbase);
    }
    __syncthreads();
    bh8 af[4], bfr[4];
#pragma unroll
    for (int m = 0; m < 4; ++m) af[m] = *(const bh8*)&As[(wr + m * 16 + c_) * 32 + r_ * 8];
#pragma unroll
    for (int n = 0; n < 4; ++n) bfr[n] = *(const bh8*)&Bs[(wc + n * 16 + c_) * 32 + r_ * 8];
#pragma unroll
    for (int m = 0; m < 4; ++m)
#pragma unroll
      for (int n = 0; n < 4; ++n) acc[m][n] = mfma16(af[m], bfr[n], acc[m][n]);
    __syncthreads();
  }
#pragma unroll
  for (int m = 0; m < 4; ++m) {
#pragma unroll
    for (int r = 0; r < 4; ++r) {
      int rowg = m0 + wr + m * 16 + r_ * 4 + r;
      size_t rb = (size_t)rowg * N;
#pragma unroll
      for (int n = 0; n < 4; ++n) {
        int colg = n0 + wc + n * 16 + c_;
        float val = acc[m][n][r];
        if (EPI == 0) {
          store_out(&C[rb + colg], val * scale);
        } else if (EPI == 1) {
          store_out(&C[rb + colg], val + ((const float*)aux)[rb + colg]);
        } else if (EPI == 2) {
          float gv = bf2f(((const u16*)aux)[rb + colg]);
          store_out(&C[rb + colg], val * (gv / (1.f + expf(-gv))));
        } else {  // EPI 3: panel (b,c,h), layout [v][i] u16, swizzled byte ^= (v&7)<<4
          int bb = rowg >> 11, t2 = rowg & 2047;
          int pan = ((bb << 5) + (t2 >> 6)) * 8 + (colg >> 8);
          int ii = t2 & 63, vv = colg & 255;
          *(u16*)((char*)C + (size_t)pan * 32768 + vv * 128 + ((ii * 2) ^ ((vv & 7) << 4)))
              = f2bf(val);
        }
      }
    }
  }
}

// ---------------- low-rank gate path: g = log_sigmoid(h@w1@w2 + b)/16 ----------------
__global__ __launch_bounds__(256)
void lowrank_k(const u16* __restrict__ h, const float* __restrict__ w1,
               const float* __restrict__ w2, const float* __restrict__ bias,
               float* __restrict__ g) {
  int row = blockIdx.x, t = threadIdx.x, lane = t & 63, wave = t >> 6;
  const u16* hr = h + (size_t)row * 2048;
  bh8 hv = *(const bh8*)&hr[t * 8];
  float p[16];
#pragma unroll
  for (int j = 0; j < 16; ++j) p[j] = 0.f;
#pragma unroll
  for (int kk = 0; kk < 8; ++kk) {
    float f = bf2f((u16)hv[kk]);
    const float* wrow = w1 + (size_t)(t * 8 + kk) * 16;
#pragma unroll
    for (int j = 0; j < 16; ++j) p[j] += f * wrow[j];
  }
#pragma unroll
  for (int j = 0; j < 16; ++j)
#pragma unroll
    for (int s = 32; s > 0; s >>= 1) p[j] += __shfl_xor(p[j], s, 64);
  __shared__ float gl[4][16];
  if (lane == 0) {
#pragma unroll
    for (int j = 0; j < 16; ++j) gl[wave][j] = p[j];
  }
  __syncthreads();
  float glow[16];
#pragma unroll
  for (int j = 0; j < 16; ++j) glow[j] = gl[0][j] + gl[1][j] + gl[2][j] + gl[3][j];
  float* grow = g + (size_t)row * 1024;
#pragma unroll
  for (int nn = 0; nn < 4; ++nn) {
    int n = nn * 256 + t;
    float z = bias[n];
#pragma unroll
    for (int j = 0; j < 16; ++j) z += glow[j] * w2[j * 1024 + n];
    float ls = fminf(z, 0.f) - log1pf(expf(-fabsf(z)));
    grow[n] = ls * (1.0f / 16.0f);
  }
}

// ---------------- gating prep (parallel over B*nc*H = 512 blocks) ----------------
// In-place: q <- q*e^b ; k <- k*e^-b. Also writes keT panels ([ch][i], swizzled) and ebl.
__global__ __launch_bounds__(128)
void gprep_k(u16* __restrict__ q, u16* __restrict__ k, const float* __restrict__ g,
             u16* __restrict__ keT, float* __restrict__ ebl) {
  int bid = blockIdx.x;            // ((b*32+c)*8+h)
  int h = bid & 7, bc = bid >> 3;
  int b = bc >> 5, c = bc & 31;
  int ch = threadIdx.x;            // 0..127
  size_t base = ((size_t)(b * 2048 + c * 64)) * 1024 + h * 128 + ch;
  char* keTp = (char*)keT + (size_t)bid * 16384 + ch * 128;
  int sw = (ch & 7) << 4;
  float bacc = 0.f;
  for (int i8 = 0; i8 < 8; ++i8) {
    u16 kp[8];
#pragma unroll
    for (int e = 0; e < 8; ++e) {
      size_t off = base + (size_t)(i8 * 8 + e) * 1024;
      bacc += g[off];
      float eb = __expf(bacc);
      float reb = __builtin_amdgcn_rcpf(eb);
      float qv = bf2f(q[off]), kv = bf2f(k[off]);
      q[off] = f2bf(qv * eb);
      u16 kev = f2bf(kv * reb);
      k[off] = kev;
      kp[e] = kev;
    }
    *(bh8*)(keTp + ((i8 * 16) ^ sw)) = *(const bh8*)kp;
  }
  ebl[(size_t)bid * 128 + ch] = __expf(bacc);
}

// ---------------- GLA chunked scan (inter + intra, MFMA only) ----------------
// grid = 64 : (b,h) x 4 HV-slices of 64. S kept fp32 master + bf16 shadow (S^T [v][ch]).
__global__ __launch_bounds__(256)
void gla_scan(const u16* __restrict__ qg, const u16* __restrict__ kg,
              const u16* __restrict__ keTg, const u16* __restrict__ vTg,
              const float* __restrict__ eblg, float* __restrict__ outp) {
  __shared__ u16 qeL[64 * 128];   // [i][ch] swizzled
  __shared__ u16 keL[64 * 128];   // [i][ch] swizzled
  __shared__ u16 kTL[128 * 64];   // [ch][i] swizzled (baked by gprep)
  __shared__ u16 vTL[64 * 64];    // [v][i]  swizzled (baked by V-GEMM)
  __shared__ u16 AL[64 * 64];     // [i][j]  swizzled
  __shared__ u16 SbL[64 * 128];   // S^T bf16 [v][ch] swizzled
  __shared__ float SfL[64][133];  // S^T fp32 master (padded)

  int t = threadIdx.x, lane = t & 63, w = t >> 6;
  int vb = blockIdx.x & 3, bh = blockIdx.x >> 2;
  int b = bh >> 3, h = bh & 7;
  int c_ = lane & 15, r_ = lane >> 4;
  f4 z4 = {0.f, 0.f, 0.f, 0.f};

  for (int i = t; i < 64 * 128; i += 256) SbL[i] = 0;
  for (int i = t; i < 64 * 133; i += 256) ((float*)SfL)[i] = 0.f;

  const char* qbase = (const char*)qg + (size_t)b * 2048 * 2048 + h * 256;
  const char* kbase = (const char*)kg + (size_t)b * 2048 * 2048 + h * 256;
  int rowoff = (t >> 4) * 2048 + (t & 15) * 16;
  int4 pq[4], pk[4], pkt[4], pvt[2];

#define LOADCH(cc)                                                              \
  {                                                                             \
    const char* qc = qbase + (size_t)(cc) * 64 * 2048;                          \
    const char* kc = kbase + (size_t)(cc) * 64 * 2048;                          \
    int panel_ = ((b * 32 + (cc)) * 8 + h);                                     \
    const char* ktc = (const char*)keTg + (size_t)panel_ * 16384;               \
    const char* vtc = (const char*)vTg + (size_t)panel_ * 32768 + vb * 8192;    \
    _Pragma("unroll")                                                           \
    for (int j = 0; j < 4; ++j) {                                               \
      pq[j] = *(const int4*)(qc + j * 16 * 2048 + rowoff);                      \
      pk[j] = *(const int4*)(kc + j * 16 * 2048 + rowoff);                      \
      pkt[j] = *(const int4*)(ktc + j * 4096 + t * 16);                         \
    }                                                                           \
    _Pragma("unroll")                                                           \
    for (int j = 0; j < 2; ++j) pvt[j] = *(const int4*)(vtc + j * 4096 + t * 16); \
  }

  LOADCH(0);
  for (int c = 0; c < 32; ++c) {
    // phase 1: LDS store (apply swizzle for qe/ke; keT/vT pre-swizzled) + prefetch c+1
#pragma unroll
    for (int j = 0; j < 4; ++j) {
      int L = j * 4096 + t * 16;
      int d = (L & ~255) | ((L & 255) ^ (((L >> 8) & 7) << 4));
      *(int4*)((char*)qeL + d) = pq[j];
      *(int4*)((char*)keL + d) = pk[j];
      *(int4*)((char*)kTL + L) = pkt[j];
    }
#pragma unroll
    for (int j = 0; j < 2; ++j) *(int4*)((char*)vTL + j * 4096 + t * 16) = pvt[j];
    if (c < 31) LOADCH(c + 1);
    int panel = ((b * 32 + c) * 8 + h);
    float eblr[2][4];
#pragma unroll
    for (int kt = 0; kt < 2; ++kt)
#pragma unroll
      for (int r = 0; r < 4; ++r)
        eblr[kt][r] = eblg[(size_t)panel * 128 + w * 32 + kt * 16 + r_ * 4 + r];
    __syncthreads();

    // phase 2: A = tril(qe@ke^T)  and  accS = keT@v
    f4 accA[4] = {z4, z4, z4, z4};
    f4 accS[2][4] = {{z4, z4, z4, z4}, {z4, z4, z4, z4}};
#pragma unroll
    for (int ks = 0; ks < 4; ++ks) {
      bh8 a = rd8(qeL, w * 16 + c_, ks * 32 + r_ * 8, 256);
#pragma unroll
      for (int n = 0; n < 4; ++n)
        accA[n] = mfma16(a, rd8(keL, n * 16 + c_, ks * 32 + r_ * 8, 256), accA[n]);
    }
#pragma unroll
    for (int ks = 0; ks < 2; ++ks) {
      bh8 bf_[4];
#pragma unroll
      for (int n = 0; n < 4; ++n) bf_[n] = rd8(vTL, n * 16 + c_, ks * 32 + r_ * 8, 128);
#pragma unroll
      for (int kt = 0; kt < 2; ++kt) {
        bh8 a = rd8(kTL, w * 32 + kt * 16 + c_, ks * 32 + r_ * 8, 128);
#pragma unroll
        for (int n = 0; n < 4; ++n) accS[kt][n] = mfma16(a, bf_[n], accS[kt][n]);
      }
    }
#pragma unroll
    for (int n = 0; n < 4; ++n)
#pragma unroll
      for (int r = 0; r < 4; ++r) {
        int i = w * 16 + r_ * 4 + r, j = n * 16 + c_;
        *(u16*)((char*)AL + i * 128 + ((j * 2) ^ ((i & 7) << 4))) =
            (j <= i) ? f2bf(accA[n][r]) : (u16)0;
      }
    __syncthreads();

    // phase 3: o = qe@S^T' + A@v
    f4 acco[4] = {z4, z4, z4, z4};
#pragma unroll
    for (int ks = 0; ks < 4; ++ks) {
      bh8 a = rd8(qeL, w * 16 + c_, ks * 32 + r_ * 8, 256);
#pragma unroll
      for (int n = 0; n < 4; ++n)
        acco[n] = mfma16(a, rd8(SbL, n * 16 + c_, ks * 32 + r_ * 8, 256), acco[n]);
    }
#pragma unroll
    for (int ks = 0; ks < 2; ++ks) {
      bh8 a = rd8(AL, w * 16 + c_, ks * 32 + r_ * 8, 128);
#pragma unroll
      for (int n = 0; n < 4; ++n)
        acco[n] = mfma16(a, rd8(vTL, n * 16 + c_, ks * 32 + r_ * 8, 128), acco[n]);
    }
    {
      size_t obase = (size_t)(b * 2048 + c * 64 + w * 16 + r_ * 4) * 2048 + h * 256 + vb * 64;
#pragma unroll
      for (int n = 0; n < 4; ++n)
#pragma unroll
        for (int r = 0; r < 4; ++r)
          outp[obase + (size_t)r * 2048 + n * 16 + c_] = acco[n][r];
    }
    __syncthreads();

    // phase 4: S = ebl * (S + accS)
#pragma unroll
    for (int kt = 0; kt < 2; ++kt)
#pragma unroll
      for (int n = 0; n < 4; ++n)
#pragma unroll
        for (int r = 0; r < 4; ++r) {
          int kk = w * 32 + kt * 16 + r_ * 4 + r;
          int vcol = n * 16 + c_;
          float nv = eblr[kt][r] * (SfL[vcol][kk] + accS[kt][n][r]);
          SfL[vcol][kk] = nv;
          *(u16*)((char*)SbL + vcol * 256 + ((kk * 2) ^ ((vcol & 7) << 4))) = f2bf(nv);
        }
    __syncthreads();
  }
#undef LOADCH
}

// ---------------- per-head RMSNorm * swish(gate) ----------------
__global__ __launch_bounds__(256)
void ogate_k(const float* __restrict__ o, const u16* __restrict__ gate,
             const float* __restrict__ gw, u16* __restrict__ og) {
  int tok = blockIdx.x, t = threadIdx.x;
  int head = t >> 5, l32 = t & 31, v0 = l32 * 8;
  size_t base = (size_t)tok * 2048 + head * 256 + v0;
  float4 a = *(const float4*)&o[base];
  float4 b = *(const float4*)&o[base + 4];
  float ov[8] = {a.x, a.y, a.z, a.w, b.x, b.y, b.z, b.w};
  float ss = 0.f;
#pragma unroll
  for (int j = 0; j < 8; ++j) ss += ov[j] * ov[j];
#pragma unroll
  for (int s = 16; s > 0; s >>= 1) ss += __shfl_xor(ss, s, 32);
  float rr = rsqrtf(ss * (1.0f / 256.0f) + 1e-6f);
#pragma unroll
  for (int j = 0; j < 8; ++j) {
    float gv = bf2f(gate[base + j]);
    float val = ov[j] * rr * gw[v0 + j];
    og[base + j] = f2bf(val * gv / (1.f + expf(-gv)));
  }
}

// ---------------- launch ----------------
extern "C" void kernel_launch(void* const* d_in, const int* in_sizes, int n_in,
                              void* d_out, int out_size, void* d_ws, size_t ws_size,
                              hipStream_t stream) {
  (void)in_sizes; (void)n_in; (void)out_size; (void)ws_size;
  const float* x = (const float*)d_in[0];
  const float* n1w = (const float*)d_in[1];
  const float* wq = (const float*)d_in[2];
  const float* wk = (const float*)d_in[3];
  const float* wv = (const float*)d_in[4];
  const float* gw1 = (const float*)d_in[5];
  const float* gw2 = (const float*)d_in[6];
  const float* gb = (const float*)d_in[7];
  const float* wg = (const float*)d_in[8];
  const float* gnw = (const float*)d_in[9];
  const float* wo = (const float*)d_in[10];
  const float* fnw = (const float*)d_in[11];
  const float* wgate = (const float*)d_in[12];
  const float* wup = (const float*)d_in[13];
  const float* wdown = (const float*)d_in[14];
  float* out = (float*)d_out;

  char* ws = (char*)d_ws;
  size_t off = 0;
  auto alloc = [&](size_t bytes) { size_t p = off; off += (bytes + 255) & ~(size_t)255; return p; };
  u16* wqT = (u16*)(ws + alloc(2ull * 1024 * 2048));
  u16* wkT = (u16*)(ws + alloc(2ull * 1024 * 2048));
  u16* wvT = (u16*)(ws + alloc(2ull * 2048 * 2048));
  u16* wgT = (u16*)(ws + alloc(2ull * 2048 * 2048));
  u16* woT = (u16*)(ws + alloc(2ull * 2048 * 2048));
  u16* wgateT = (u16*)(ws + alloc(2ull * 5504 * 2048));
  u16* wupT = (u16*)(ws + alloc(2ull * 5504 * 2048));
  u16* wdT = (u16*)(ws + alloc(2ull * 2048 * 5504));
  u16* h_bf = (u16*)(ws + alloc(2ull * 4096 * 2048));   // h -> keT panels -> og
  u16* q_bf = (u16*)(ws + alloc(2ull * 4096 * 1024));   // q -> qe (in place) -> h2
  u16* k_bf = (u16*)(ws + alloc(2ull * 4096 * 1024));   // k -> ke (in place)
  u16* vT_g = (u16*)(ws + alloc(2ull * 4096 * 2048));   // v panels [512][256][64] swizzled
  u16* gate_bf = (u16*)(ws + alloc(2ull * 4096 * 2048));
  float* g_f = (float*)(ws + alloc(4ull * 4096 * 1024));
  float* o_f = (float*)(ws + alloc(4ull * 4096 * 2048));  // later reused as x2
  u16* gH = (u16*)(ws + alloc(2ull * 4096 * 5504));       // later reused as mid
  float* ebl_g = (float*)(ws + alloc(4ull * 512 * 128));
  u16* keT_g = h_bf;
  u16* og = h_bf;
  u16* h2 = q_bf;
  float* x2 = o_f;
  u16* mid = gH;

  dim3 blk(256);
  wtrans_k<<<dim3(32, 64), blk, 0, stream>>>(wq, wqT, 2048, 1024);
  wtrans_k<<<dim3(32, 64), blk, 0, stream>>>(wk, wkT, 2048, 1024);
  wtrans_k<<<dim3(64, 64), blk, 0, stream>>>(wv, wvT, 2048, 2048);
  wtrans_k<<<dim3(64, 64), blk, 0, stream>>>(wg, wgT, 2048, 2048);
  wtrans_k<<<dim3(64, 64), blk, 0, stream>>>(wo, woT, 2048, 2048);
  wtrans_k<<<dim3(172, 64), blk, 0, stream>>>(wgate, wgateT, 2048, 5504);
  wtrans_k<<<dim3(172, 64), blk, 0, stream>>>(wup, wupT, 2048, 5504);
  wtrans_k<<<dim3(64, 172), blk, 0, stream>>>(wdown, wdT, 5504, 2048);

  rmsnorm_k<<<4096, blk, 0, stream>>>(x, n1w, h_bf);

  gemm_bt<0, u16><<<dim3(8, 32), blk, 0, stream>>>(h_bf, wqT, q_bf, nullptr, 0.08838834764831845f, 4096, 1024, 2048);
  gemm_bt<0, u16><<<dim3(8, 32), blk, 0, stream>>>(h_bf, wkT, k_bf, nullptr, 1.f, 4096, 1024, 2048);
  gemm_bt<3, u16><<<dim3(16, 32), blk, 0, stream>>>(h_bf, wvT, vT_g, nullptr, 1.f, 4096, 2048, 2048);
  gemm_bt<0, u16><<<dim3(16, 32), blk, 0, stream>>>(h_bf, wgT, gate_bf, nullptr, 1.f, 4096, 2048, 2048);
  lowrank_k<<<4096, blk, 0, stream>>>(h_bf, gw1, gw2, gb, g_f);

  // h_bf dead from here; reuse as keT panels
  gprep_k<<<512, dim3(128), 0, stream>>>(q_bf, k_bf, g_f, keT_g, ebl_g);

  gla_scan<<<64, blk, 0, stream>>>(q_bf, k_bf, keT_g, vT_g, ebl_g, o_f);

  ogate_k<<<4096, blk, 0, stream>>>(o_f, gate_bf, gnw, og);

  gemm_bt<1, float><<<dim3(16, 32), blk, 0, stream>>>(og, woT, x2, x, 1.f, 4096, 2048, 2048);

  rmsnorm_k<<<4096, blk, 0, stream>>>(x2, fnw, h2);

  gemm_bt<0, u16><<<dim3(43, 32), blk, 0, stream>>>(h2, wgateT, gH, nullptr, 1.f, 4096, 5504, 2048);
  gemm_bt<2, u16><<<dim3(43, 32), blk, 0, stream>>>(h2, wupT, mid, gH, 1.f, 4096, 5504, 2048);
  gemm_bt<1, float><<<dim3(16, 32), blk, 0, stream>>>(mid, wdT, out, x2, 1.f, 4096, 2048, 5504);
}

// Round 4
// 1080.659 us; speedup vs baseline: 1.3091x; 1.0555x over previous
//
#include <hip/hip_runtime.h>

typedef unsigned short u16;
typedef __attribute__((ext_vector_type(8))) short bh8;   // 8 x bf16 bits (4 VGPRs)
typedef __attribute__((ext_vector_type(4))) float f4;    // MFMA accumulator

__device__ __forceinline__ float bf2f(u16 u) {
  union { unsigned int i; float f; } x; x.i = ((unsigned int)u) << 16; return x.f;
}
__device__ __forceinline__ u16 f2bf(float f) {
  union { float f; unsigned int i; } x; x.f = f;
  unsigned int r = x.i + 0x7fffu + ((x.i >> 16) & 1u);
  return (u16)(r >> 16);
}
__device__ __forceinline__ f4 mfma16(bh8 a, bh8 b, f4 c) {
  return __builtin_amdgcn_mfma_f32_16x16x32_bf16(a, b, c, 0, 0, 0);
}
__device__ __forceinline__ void gload16(const void* g, void* l) {
  __builtin_amdgcn_global_load_lds(
      (const __attribute__((address_space(1))) void*)g,
      (__attribute__((address_space(3))) void*)l, 16, 0, 0);
}

// swizzled LDS read: dense row-major array, byte-in-row XOR'd by (row&7)<<4
__device__ __forceinline__ bh8 rd8(const u16* arr, int row, int col, int rowbytes) {
  return *(const bh8*)((const char*)arr + row * rowbytes + ((col * 2) ^ ((row & 7) << 4)));
}

// ---------------- weight transpose: fp32 [R][C] -> bf16 [C*rmul+roff][R] ----------------
__global__ __launch_bounds__(256)
void wtrans_k(const float* __restrict__ src, u16* __restrict__ dst, int R, int C,
              int rmul, int roff) {
  __shared__ float tile[32][33];
  int tx = threadIdx.x & 31, ty = threadIdx.x >> 5;
  int c0 = blockIdx.x * 32, r0 = blockIdx.y * 32;
#pragma unroll
  for (int yy = 0; yy < 32; yy += 8)
    tile[ty + yy][tx] = src[(size_t)(r0 + ty + yy) * C + c0 + tx];
  __syncthreads();
#pragma unroll
  for (int yy = 0; yy < 32; yy += 8)
    dst[(size_t)((c0 + ty + yy) * rmul + roff) * R + r0 + tx] = f2bf(tile[tx][ty + yy]);
}

// ---------------- RMSNorm over D=2048, fp32 in -> bf16 out ----------------
__global__ __launch_bounds__(256)
void rmsnorm_k(const float* __restrict__ x, const float* __restrict__ w,
               u16* __restrict__ out) {
  int row = blockIdx.x, t = threadIdx.x;
  const float* xr = x + (size_t)row * 2048;
  float4 a = ((const float4*)xr)[t * 2];
  float4 b = ((const float4*)xr)[t * 2 + 1];
  float ss = a.x*a.x + a.y*a.y + a.z*a.z + a.w*a.w
           + b.x*b.x + b.y*b.y + b.z*b.z + b.w*b.w;
#pragma unroll
  for (int s = 32; s > 0; s >>= 1) ss += __shfl_xor(ss, s, 64);
  __shared__ float red[4];
  if ((t & 63) == 0) red[t >> 6] = ss;
  __syncthreads();
  float rr = rsqrtf((red[0] + red[1] + red[2] + red[3]) * (1.0f / 2048.0f) + 1e-6f);
  float v[8] = {a.x, a.y, a.z, a.w, b.x, b.y, b.z, b.w};
  int c0 = t * 8;
  u16* orow = out + (size_t)row * 2048 + c0;
#pragma unroll
  for (int j = 0; j < 8; ++j) orow[j] = f2bf(v[j] * rr * w[c0 + j]);
}

// ======================= gemm2: phase-pipelined GEMM =======================
// C[M][N] = A[M][K] @ Bt[N][K]^T. BM=128, BN=256, BK=32, 256 thr (4 waves),
// 3 LDS slots of (A 8KB + B 16KB), counted vmcnt(6), XOR-swizzled chunks.
// Tail fix: ALWAYS stage (wrapped tile index) so the vmcnt(6) ladder is
// uniform; dummy tiles only touch slots that are never read again.
// EPI 1: C fp32 = acc + auxF32[row*N+col]
// EPI 4: col<2048 -> v panel write (scan layout); else gate_bf (aux) plain
// EPI 5: col<1024 -> q (scale) ; else k (aux)
// EPI 6: interleaved gate/up; odd lanes store silu(gate)*up to C[row*5504+col/2]
template <int EPI, typename OutT>
__global__ __launch_bounds__(256, 2)
void gemm2(const u16* __restrict__ A, const u16* __restrict__ Bt,
           OutT* __restrict__ C, void* __restrict__ aux, float scale,
           int M, int N, int K, int gx) {
  __shared__ char lds[73728];  // 3 * 24576
  int t = threadIdx.x, lane = t & 63, w = t >> 6;
  int c_ = lane & 15, r_ = lane >> 4;

  // bijective XCD swizzle (grids here are multiples of 8)
  int nwg = gridDim.x;
  int wg = (blockIdx.x & 7) * (nwg >> 3) + (blockIdx.x >> 3);
  int gy = nwg / gx;
  int bx = wg / gy, by = wg % gy;
  int m0 = by * 128, n0 = bx * 256;

  const size_t ldA = K, ldB = K;

  // stage one A-half (128x32 tile half h: rows h*64..h*64+63): 1 load/thread
  auto stageA = [&](int kt, int slot, int h) {
    int p = h * 256 + t;                    // physical 16B chunk in A region
    int cc = p ^ ((p >> 3) & 7);            // involution -> logical chunk
    int m = cc >> 2, kb = cc & 3;
    const char* src = (const char*)A + ((size_t)(m0 + m) * ldA + kt * 32) * 2 + kb * 16;
    char* dst = lds + slot * 24576 + h * 4096 + w * 1024;
    gload16(src, dst);
  };
  // stage B quarter (q half of 256 rows, j sub): 2 loads/thread per phase
  auto stageB = [&](int kt, int slot, int qq, int j) {
    int p = qq * 512 + j * 256 + t;
    int cc = p ^ ((p >> 3) & 7);
    int n = cc >> 2, kb = cc & 3;
    const char* src = (const char*)Bt + ((size_t)(n0 + n) * ldB + kt * 32) * 2 + kb * 16;
    char* dst = lds + slot * 24576 + 8192 + (qq * 8192 + j * 4096) + w * 1024;
    gload16(src, dst);
  };
  auto rdA = [&](int slot, int mb) -> bh8 {
    int cc = (mb * 16 + c_) * 4 + r_;
    int p = cc ^ ((cc >> 3) & 7);
    return *(const bh8*)(lds + slot * 24576 + p * 16);
  };
  auto rdB = [&](int slot, int nb) -> bh8 {
    int cc = (w * 64 + nb * 16 + c_) * 4 + r_;
    int p = cc ^ ((cc >> 3) & 7);
    return *(const bh8*)(lds + slot * 24576 + 8192 + p * 16);
  };

  f4 z4 = {0.f, 0.f, 0.f, 0.f};
  f4 acc[8][4];
#pragma unroll
  for (int mb = 0; mb < 8; ++mb)
#pragma unroll
    for (int nb = 0; nb < 4; ++nb) acc[mb][nb] = z4;

  int NT = K >> 5;
  // prologue: stage tiles 0 and 1
  stageA(0, 0, 0); stageB(0, 0, 0, 0); stageB(0, 0, 0, 1);
  stageA(0, 0, 1); stageB(0, 0, 1, 0); stageB(0, 0, 1, 1);
  stageA(1, 1, 0); stageB(1, 1, 0, 0); stageB(1, 1, 0, 1);
  stageA(1, 1, 1); stageB(1, 1, 1, 0); stageB(1, 1, 1, 1);
  asm volatile("s_waitcnt vmcnt(6)" ::: "memory");  // tile 0 landed
  __builtin_amdgcn_s_barrier();
  asm volatile("" ::: "memory");

  int slot = 0;
  for (int kt = 0; kt < NT; ++kt) {
    int fslot = slot + 2; if (fslot >= 3) fslot -= 3;
    int kts = kt + 2; if (kts >= NT) kts -= NT;  // wrapped dummy at tail
    // ---- phase 0 ----
    bh8 bfr[4], afr[4];
#pragma unroll
    for (int nb = 0; nb < 4; ++nb) bfr[nb] = rdB(slot, nb);
#pragma unroll
    for (int mb = 0; mb < 4; ++mb) afr[mb] = rdA(slot, mb);
    stageA(kts, fslot, 0); stageB(kts, fslot, 0, 0); stageB(kts, fslot, 0, 1);
    __builtin_amdgcn_s_barrier();
    asm volatile("s_waitcnt lgkmcnt(0)" ::: "memory");
    __builtin_amdgcn_sched_barrier(0);
    __builtin_amdgcn_s_setprio(1);
#pragma unroll
    for (int mb = 0; mb < 4; ++mb)
#pragma unroll
      for (int nb = 0; nb < 4; ++nb) acc[mb][nb] = mfma16(afr[mb], bfr[nb], acc[mb][nb]);
    __builtin_amdgcn_s_setprio(0);
    __builtin_amdgcn_sched_barrier(0);
    __builtin_amdgcn_s_barrier();
    asm volatile("" ::: "memory");
    // ---- phase 1 ----
#pragma unroll
    for (int mb = 0; mb < 4; ++mb) afr[mb] = rdA(slot, mb + 4);
    stageA(kts, fslot, 1); stageB(kts, fslot, 1, 0); stageB(kts, fslot, 1, 1);
    asm volatile("s_waitcnt vmcnt(6)" ::: "memory");  // forces tile kt+1 landed
    __builtin_amdgcn_s_barrier();
    asm volatile("s_waitcnt lgkmcnt(0)" ::: "memory");
    __builtin_amdgcn_sched_barrier(0);
    __builtin_amdgcn_s_setprio(1);
#pragma unroll
    for (int mb = 0; mb < 4; ++mb)
#pragma unroll
      for (int nb = 0; nb < 4; ++nb) acc[mb + 4][nb] = mfma16(afr[mb], bfr[nb], acc[mb + 4][nb]);
    __builtin_amdgcn_s_setprio(0);
    __builtin_amdgcn_sched_barrier(0);
    __builtin_amdgcn_s_barrier();
    asm volatile("" ::: "memory");
    slot = (slot + 1 == 3) ? 0 : slot + 1;
  }
  asm volatile("s_waitcnt vmcnt(0)" ::: "memory");  // drain dummy stages

  // ---- epilogue ----
#pragma unroll
  for (int mb = 0; mb < 8; ++mb) {
#pragma unroll
    for (int rr = 0; rr < 4; ++rr) {
      int row = m0 + mb * 16 + r_ * 4 + rr;
#pragma unroll
      for (int nb = 0; nb < 4; ++nb) {
        int col = n0 + w * 64 + nb * 16 + c_;
        float val = acc[mb][nb][rr];
        if (EPI == 1) {
          ((float*)C)[(size_t)row * N + col] = val + ((const float*)aux)[(size_t)row * N + col];
        } else if (EPI == 5) {
          if (col < 1024) ((u16*)C)[(size_t)row * 1024 + col] = f2bf(val * scale);
          else ((u16*)aux)[(size_t)row * 1024 + col - 1024] = f2bf(val);
        } else if (EPI == 4) {
          if (col < 2048) {
            int bb = row >> 11, t2 = row & 2047;
            int pan = ((bb << 5) + (t2 >> 6)) * 8 + (col >> 8);
            int ii = t2 & 63, vv = col & 255;
            *(u16*)((char*)C + (size_t)pan * 32768 + vv * 128 + ((ii * 2) ^ ((vv & 7) << 4)))
                = f2bf(val);
          } else {
            ((u16*)aux)[(size_t)row * 2048 + col - 2048] = f2bf(val);
          }
        } else if (EPI == 6) {
          float other = __shfl_xor(val, 1, 64);
          if (lane & 1) {
            float gv = other;
            ((u16*)C)[(size_t)row * 5504 + (col >> 1)] = f2bf(val * (gv / (1.f + expf(-gv))));
          }
        }
      }
    }
  }
}

// ---------------- low-rank gate path: g = log_sigmoid(h@w1@w2 + b)/16 ----------------
__global__ __launch_bounds__(256)
void lowrank_k(const u16* __restrict__ h, const float* __restrict__ w1,
               const float* __restrict__ w2, const float* __restrict__ bias,
               float* __restrict__ g) {
  int row = blockIdx.x, t = threadIdx.x, lane = t & 63, wave = t >> 6;
  const u16* hr = h + (size_t)row * 2048;
  bh8 hv = *(const bh8*)&hr[t * 8];
  float p[16];
#pragma unroll
  for (int j = 0; j < 16; ++j) p[j] = 0.f;
#pragma unroll
  for (int kk = 0; kk < 8; ++kk) {
    float f = bf2f((u16)hv[kk]);
    const float* wrow = w1 + (size_t)(t * 8 + kk) * 16;
#pragma unroll
    for (int j = 0; j < 16; ++j) p[j] += f * wrow[j];
  }
#pragma unroll
  for (int j = 0; j < 16; ++j)
#pragma unroll
    for (int s = 32; s > 0; s >>= 1) p[j] += __shfl_xor(p[j], s, 64);
  __shared__ float gl[4][16];
  if (lane == 0) {
#pragma unroll
    for (int j = 0; j < 16; ++j) gl[wave][j] = p[j];
  }
  __syncthreads();
  float glow[16];
#pragma unroll
  for (int j = 0; j < 16; ++j) glow[j] = gl[0][j] + gl[1][j] + gl[2][j] + gl[3][j];
  float* grow = g + (size_t)row * 1024;
#pragma unroll
  for (int nn = 0; nn < 4; ++nn) {
    int n = nn * 256 + t;
    float z = bias[n];
#pragma unroll
    for (int j = 0; j < 16; ++j) z += glow[j] * w2[j * 1024 + n];
    float ls = fminf(z, 0.f) - log1pf(expf(-fabsf(z)));
    grow[n] = ls * (1.0f / 16.0f);
  }
}

// ---------------- gating prep (parallel over B*nc*H = 512 blocks) ----------------
__global__ __launch_bounds__(128)
void gprep_k(u16* __restrict__ q, u16* __restrict__ k, const float* __restrict__ g,
             u16* __restrict__ keT, float* __restrict__ ebl) {
  int bid = blockIdx.x;            // ((b*32+c)*8+h)
  int h = bid & 7, bc = bid >> 3;
  int b = bc >> 5, c = bc & 31;
  int ch = threadIdx.x;            // 0..127
  size_t base = ((size_t)(b * 2048 + c * 64)) * 1024 + h * 128 + ch;
  char* keTp = (char*)keT + (size_t)bid * 16384 + ch * 128;
  int sw = (ch & 7) << 4;
  float bacc = 0.f;
  for (int i8 = 0; i8 < 8; ++i8) {
    u16 kp[8];
#pragma unroll
    for (int e = 0; e < 8; ++e) {
      size_t off = base + (size_t)(i8 * 8 + e) * 1024;
      bacc += g[off];
      float eb = __expf(bacc);
      float reb = __builtin_amdgcn_rcpf(eb);
      float qv = bf2f(q[off]), kv = bf2f(k[off]);
      q[off] = f2bf(qv * eb);
      u16 kev = f2bf(kv * reb);
      k[off] = kev;
      kp[e] = kev;
    }
    *(bh8*)(keTp + ((i8 * 16) ^ sw)) = *(const bh8*)kp;
  }
  ebl[(size_t)bid * 128 + ch] = __expf(bacc);
}

// ---------------- GLA chunked scan (inter + intra, MFMA only) ----------------
__global__ __launch_bounds__(256)
void gla_scan(const u16* __restrict__ qg, const u16* __restrict__ kg,
              const u16* __restrict__ keTg, const u16* __restrict__ vTg,
              const float* __restrict__ eblg, float* __restrict__ outp) {
  __shared__ u16 qeL[64 * 128];   // [i][ch] swizzled
  __shared__ u16 keL[64 * 128];   // [i][ch] swizzled
  __shared__ u16 kTL[128 * 64];   // [ch][i] swizzled (baked by gprep)
  __shared__ u16 vTL[64 * 64];    // [v][i]  swizzled (baked by V-GEMM)
  __shared__ u16 AL[64 * 64];     // [i][j]  swizzled
  __shared__ u16 SbL[64 * 128];   // S^T bf16 [v][ch] swizzled
  __shared__ float SfL[64][133];  // S^T fp32 master (padded)

  int t = threadIdx.x, lane = t & 63, w = t >> 6;
  int vb = blockIdx.x & 3, bh = blockIdx.x >> 2;
  int b = bh >> 3, h = bh & 7;
  int c_ = lane & 15, r_ = lane >> 4;
  f4 z4 = {0.f, 0.f, 0.f, 0.f};

  for (int i = t; i < 64 * 128; i += 256) SbL[i] = 0;
  for (int i = t; i < 64 * 133; i += 256) ((float*)SfL)[i] = 0.f;

  const char* qbase = (const char*)qg + (size_t)b * 2048 * 2048 + h * 256;
  const char* kbase = (const char*)kg + (size_t)b * 2048 * 2048 + h * 256;
  int rowoff = (t >> 4) * 2048 + (t & 15) * 16;
  int4 pq[4], pk[4], pkt[4], pvt[2];

#define LOADCH(cc)                                                              \
  {                                                                             \
    const char* qc = qbase + (size_t)(cc) * 64 * 2048;                          \
    const char* kc = kbase + (size_t)(cc) * 64 * 2048;                          \
    int panel_ = ((b * 32 + (cc)) * 8 + h);                                     \
    const char* ktc = (const char*)keTg + (size_t)panel_ * 16384;               \
    const char* vtc = (const char*)vTg + (size_t)panel_ * 32768 + vb * 8192;    \
    _Pragma("unroll")                                                           \
    for (int j = 0; j < 4; ++j) {                                               \
      pq[j] = *(const int4*)(qc + j * 16 * 2048 + rowoff);                      \
      pk[j] = *(const int4*)(kc + j * 16 * 2048 + rowoff);                      \
      pkt[j] = *(const int4*)(ktc + j * 4096 + t * 16);                         \
    }                                                                           \
    _Pragma("unroll")                                                           \
    for (int j = 0; j < 2; ++j) pvt[j] = *(const int4*)(vtc + j * 4096 + t * 16); \
  }

  LOADCH(0);
  for (int c = 0; c < 32; ++c) {
#pragma unroll
    for (int j = 0; j < 4; ++j) {
      int L = j * 4096 + t * 16;
      int d = (L & ~255) | ((L & 255) ^ (((L >> 8) & 7) << 4));
      *(int4*)((char*)qeL + d) = pq[j];
      *(int4*)((char*)keL + d) = pk[j];
      *(int4*)((char*)kTL + L) = pkt[j];
    }
#pragma unroll
    for (int j = 0; j < 2; ++j) *(int4*)((char*)vTL + j * 4096 + t * 16) = pvt[j];
    if (c < 31) LOADCH(c + 1);
    int panel = ((b * 32 + c) * 8 + h);
    float eblr[2][4];
#pragma unroll
    for (int kt = 0; kt < 2; ++kt)
#pragma unroll
      for (int r = 0; r < 4; ++r)
        eblr[kt][r] = eblg[(size_t)panel * 128 + w * 32 + kt * 16 + r_ * 4 + r];
    __syncthreads();

    // phase 2: A = tril(qe@ke^T)  and  accS = keT@v
    f4 accA[4] = {z4, z4, z4, z4};
    f4 accS[2][4] = {{z4, z4, z4, z4}, {z4, z4, z4, z4}};
#pragma unroll
    for (int ks = 0; ks < 4; ++ks) {
      bh8 a = rd8(qeL, w * 16 + c_, ks * 32 + r_ * 8, 256);
#pragma unroll
      for (int n = 0; n < 4; ++n)
        accA[n] = mfma16(a, rd8(keL, n * 16 + c_, ks * 32 + r_ * 8, 256), accA[n]);
    }
#pragma unroll
    for (int ks = 0; ks < 2; ++ks) {
      bh8 bf_[4];
#pragma unroll
      for (int n = 0; n < 4; ++n) bf_[n] = rd8(vTL, n * 16 + c_, ks * 32 + r_ * 8, 128);
#pragma unroll
      for (int kt = 0; kt < 2; ++kt) {
        bh8 a = rd8(kTL, w * 32 + kt * 16 + c_, ks * 32 + r_ * 8, 128);
#pragma unroll
        for (int n = 0; n < 4; ++n) accS[kt][n] = mfma16(a, bf_[n], accS[kt][n]);
      }
    }
#pragma unroll
    for (int n = 0; n < 4; ++n)
#pragma unroll
      for (int r = 0; r < 4; ++r) {
        int i = w * 16 + r_ * 4 + r, j = n * 16 + c_;
        *(u16*)((char*)AL + i * 128 + ((j * 2) ^ ((i & 7) << 4))) =
            (j <= i) ? f2bf(accA[n][r]) : (u16)0;
      }
    __syncthreads();

    // phase 3: o = qe@S^T' + A@v
    f4 acco[4] = {z4, z4, z4, z4};
#pragma unroll
    for (int ks = 0; ks < 4; ++ks) {
      bh8 a = rd8(qeL, w * 16 + c_, ks * 32 + r_ * 8, 256);
#pragma unroll
      for (int n = 0; n < 4; ++n)
        acco[n] = mfma16(a, rd8(SbL, n * 16 + c_, ks * 32 + r_ * 8, 256), acco[n]);
    }
#pragma unroll
    for (int ks = 0; ks < 2; ++ks) {
      bh8 a = rd8(AL, w * 16 + c_, ks * 32 + r_ * 8, 128);
#pragma unroll
      for (int n = 0; n < 4; ++n)
        acco[n] = mfma16(a, rd8(vTL, n * 16 + c_, ks * 32 + r_ * 8, 128), acco[n]);
    }
    {
      size_t obase = (size_t)(b * 2048 + c * 64 + w * 16 + r_ * 4) * 2048 + h * 256 + vb * 64;
#pragma unroll
      for (int n = 0; n < 4; ++n)
#pragma unroll
        for (int r = 0; r < 4; ++r)
          outp[obase + (size_t)r * 2048 + n * 16 + c_] = acco[n][r];
    }
    __syncthreads();

    // phase 4: S = ebl * (S + accS)
#pragma unroll
    for (int kt = 0; kt < 2; ++kt)
#pragma unroll
      for (int n = 0; n < 4; ++n)
#pragma unroll
        for (int r = 0; r < 4; ++r) {
          int kk = w * 32 + kt * 16 + r_ * 4 + r;
          int vcol = n * 16 + c_;
          float nv = eblr[kt][r] * (SfL[vcol][kk] + accS[kt][n][r]);
          SfL[vcol][kk] = nv;
          *(u16*)((char*)SbL + vcol * 256 + ((kk * 2) ^ ((vcol & 7) << 4))) = f2bf(nv);
        }
    __syncthreads();
  }
#undef LOADCH
}

// ---------------- per-head RMSNorm * swish(gate) ----------------
__global__ __launch_bounds__(256)
void ogate_k(const float* __restrict__ o, const u16* __restrict__ gate,
             const float* __restrict__ gw, u16* __restrict__ og) {
  int tok = blockIdx.x, t = threadIdx.x;
  int head = t >> 5, l32 = t & 31, v0 = l32 * 8;
  size_t base = (size_t)tok * 2048 + head * 256 + v0;
  float4 a = *(const float4*)&o[base];
  float4 b = *(const float4*)&o[base + 4];
  float ov[8] = {a.x, a.y, a.z, a.w, b.x, b.y, b.z, b.w};
  float ss = 0.f;
#pragma unroll
  for (int j = 0; j < 8; ++j) ss += ov[j] * ov[j];
#pragma unroll
  for (int s = 16; s > 0; s >>= 1) ss += __shfl_xor(ss, s, 32);
  float rr = rsqrtf(ss * (1.0f / 256.0f) + 1e-6f);
#pragma unroll
  for (int j = 0; j < 8; ++j) {
    float gv = bf2f(gate[base + j]);
    float val = ov[j] * rr * gw[v0 + j];
    og[base + j] = f2bf(val * gv / (1.f + expf(-gv)));
  }
}

// ---------------- launch ----------------
extern "C" void kernel_launch(void* const* d_in, const int* in_sizes, int n_in,
                              void* d_out, int out_size, void* d_ws, size_t ws_size,
                              hipStream_t stream) {
  (void)in_sizes; (void)n_in; (void)out_size; (void)ws_size;
  const float* x = (const float*)d_in[0];
  const float* n1w = (const float*)d_in[1];
  const float* wq = (const float*)d_in[2];
  const float* wk = (const float*)d_in[3];
  const float* wv = (const float*)d_in[4];
  const float* gw1 = (const float*)d_in[5];
  const float* gw2 = (const float*)d_in[6];
  const float* gb = (const float*)d_in[7];
  const float* wg = (const float*)d_in[8];
  const float* gnw = (const float*)d_in[9];
  const float* wo = (const float*)d_in[10];
  const float* fnw = (const float*)d_in[11];
  const float* wgate = (const float*)d_in[12];
  const float* wup = (const float*)d_in[13];
  const float* wdown = (const float*)d_in[14];
  float* out = (float*)d_out;

  char* ws = (char*)d_ws;
  size_t off = 0;
  auto alloc = [&](size_t bytes) { size_t p = off; off += (bytes + 255) & ~(size_t)255; return p; };
  u16* wqT = (u16*)(ws + alloc(2ull * 1024 * 2048));   // [contiguous with wkT -> qk Bt]
  u16* wkT = (u16*)(ws + alloc(2ull * 1024 * 2048));
  u16* wvT = (u16*)(ws + alloc(2ull * 2048 * 2048));   // [contiguous with wgT -> vg Bt]
  u16* wgT = (u16*)(ws + alloc(2ull * 2048 * 2048));
  u16* woT = (u16*)(ws + alloc(2ull * 2048 * 2048));
  u16* btGU = (u16*)(ws + alloc(2ull * 11008 * 2048)); // interleaved gate/up
  u16* wdT = (u16*)(ws + alloc(2ull * 2048 * 5504));
  u16* h_bf = (u16*)(ws + alloc(2ull * 4096 * 2048));  // h -> keT panels -> og
  u16* q_bf = (u16*)(ws + alloc(2ull * 4096 * 1024));  // q -> qe (in place) -> h2
  u16* k_bf = (u16*)(ws + alloc(2ull * 4096 * 1024));  // k -> ke (in place)
  u16* vT_g = (u16*)(ws + alloc(2ull * 4096 * 2048));  // v panels [512][256][64] swizzled
  u16* gate_bf = (u16*)(ws + alloc(2ull * 4096 * 2048));
  float* g_f = (float*)(ws + alloc(4ull * 4096 * 1024));
  float* o_f = (float*)(ws + alloc(4ull * 4096 * 2048));  // later reused as x2
  u16* mid = (u16*)(ws + alloc(2ull * 4096 * 5504));
  float* ebl_g = (float*)(ws + alloc(4ull * 512 * 128));
  u16* keT_g = h_bf;
  u16* og = h_bf;
  u16* h2 = q_bf;
  float* x2 = o_f;

  dim3 blk(256);
  wtrans_k<<<dim3(32, 64), blk, 0, stream>>>(wq, wqT, 2048, 1024, 1, 0);
  wtrans_k<<<dim3(32, 64), blk, 0, stream>>>(wk, wkT, 2048, 1024, 1, 0);
  wtrans_k<<<dim3(64, 64), blk, 0, stream>>>(wv, wvT, 2048, 2048, 1, 0);
  wtrans_k<<<dim3(64, 64), blk, 0, stream>>>(wg, wgT, 2048, 2048, 1, 0);
  wtrans_k<<<dim3(64, 64), blk, 0, stream>>>(wo, woT, 2048, 2048, 1, 0);
  wtrans_k<<<dim3(172, 64), blk, 0, stream>>>(wgate, btGU, 2048, 5504, 2, 0);
  wtrans_k<<<dim3(172, 64), blk, 0, stream>>>(wup, btGU, 2048, 5504, 2, 1);
  wtrans_k<<<dim3(64, 172), blk, 0, stream>>>(wdown, wdT, 5504, 2048, 1, 0);

  rmsnorm_k<<<4096, blk, 0, stream>>>(x, n1w, h_bf);

  // q+k fused (Bt = wqT|wkT contiguous), v+gate fused (wvT|wgT contiguous)
  gemm2<5, u16><<<256, blk, 0, stream>>>(h_bf, wqT, q_bf, k_bf, 0.08838834764831845f,
                                         4096, 2048, 2048, 8);
  gemm2<4, u16><<<512, blk, 0, stream>>>(h_bf, wvT, vT_g, gate_bf, 1.f,
                                         4096, 4096, 2048, 16);
  lowrank_k<<<4096, blk, 0, stream>>>(h_bf, gw1, gw2, gb, g_f);

  // h_bf dead from here; reuse as keT panels
  gprep_k<<<512, dim3(128), 0, stream>>>(q_bf, k_bf, g_f, keT_g, ebl_g);

  gla_scan<<<64, blk, 0, stream>>>(q_bf, k_bf, keT_g, vT_g, ebl_g, o_f);

  ogate_k<<<4096, blk, 0, stream>>>(o_f, gate_bf, gnw, og);

  gemm2<1, float><<<256, blk, 0, stream>>>(og, woT, x2, (void*)x, 1.f,
                                           4096, 2048, 2048, 8);

  rmsnorm_k<<<4096, blk, 0, stream>>>(x2, fnw, h2);

  gemm2<6, u16><<<1376, blk, 0, stream>>>(h2, btGU, mid, nullptr, 1.f,
                                          4096, 11008, 2048, 43);
  gemm2<1, float><<<256, blk, 0, stream>>>(mid, wdT, out, x2, 1.f,
                                           4096, 2048, 5504, 8);
}

// Round 5
// 1017.475 us; speedup vs baseline: 1.3904x; 1.0621x over previous
//
#include <hip/hip_runtime.h>

typedef unsigned short u16;
typedef __attribute__((ext_vector_type(8))) short bh8;   // 8 x bf16 bits (4 VGPRs)
typedef __attribute__((ext_vector_type(4))) float f4;    // MFMA accumulator

__device__ __forceinline__ float bf2f(u16 u) {
  union { unsigned int i; float f; } x; x.i = ((unsigned int)u) << 16; return x.f;
}
__device__ __forceinline__ u16 f2bf(float f) {
  union { float f; unsigned int i; } x; x.f = f;
  unsigned int r = x.i + 0x7fffu + ((x.i >> 16) & 1u);
  return (u16)(r >> 16);
}
__device__ __forceinline__ f4 mfma16(bh8 a, bh8 b, f4 c) {
  return __builtin_amdgcn_mfma_f32_16x16x32_bf16(a, b, c, 0, 0, 0);
}
__device__ __forceinline__ void gload16(const void* g, void* l) {
  __builtin_amdgcn_global_load_lds(
      (const __attribute__((address_space(1))) void*)g,
      (__attribute__((address_space(3))) void*)l, 16, 0, 0);
}

// swizzled LDS read: dense row-major array, byte-in-row XOR'd by (row&7)<<4
__device__ __forceinline__ bh8 rd8(const u16* arr, int row, int col, int rowbytes) {
  return *(const bh8*)((const char*)arr + row * rowbytes + ((col * 2) ^ ((row & 7) << 4)));
}

// ---------------- weight transpose: fp32 [R][C] -> bf16 [C*rmul+roff][R] ----------------
__global__ __launch_bounds__(256)
void wtrans_k(const float* __restrict__ src, u16* __restrict__ dst, int R, int C,
              int rmul, int roff) {
  __shared__ float tile[32][33];
  int tx = threadIdx.x & 31, ty = threadIdx.x >> 5;
  int c0 = blockIdx.x * 32, r0 = blockIdx.y * 32;
#pragma unroll
  for (int yy = 0; yy < 32; yy += 8)
    tile[ty + yy][tx] = src[(size_t)(r0 + ty + yy) * C + c0 + tx];
  __syncthreads();
#pragma unroll
  for (int yy = 0; yy < 32; yy += 8)
    dst[(size_t)((c0 + ty + yy) * rmul + roff) * R + r0 + tx] = f2bf(tile[tx][ty + yy]);
}

// ---------------- RMSNorm over D=2048, fp32 in -> bf16 out ----------------
__global__ __launch_bounds__(256)
void rmsnorm_k(const float* __restrict__ x, const float* __restrict__ w,
               u16* __restrict__ out) {
  int row = blockIdx.x, t = threadIdx.x;
  const float* xr = x + (size_t)row * 2048;
  float4 a = ((const float4*)xr)[t * 2];
  float4 b = ((const float4*)xr)[t * 2 + 1];
  float ss = a.x*a.x + a.y*a.y + a.z*a.z + a.w*a.w
           + b.x*b.x + b.y*b.y + b.z*b.z + b.w*b.w;
#pragma unroll
  for (int s = 32; s > 0; s >>= 1) ss += __shfl_xor(ss, s, 64);
  __shared__ float red[4];
  if ((t & 63) == 0) red[t >> 6] = ss;
  __syncthreads();
  float rr = rsqrtf((red[0] + red[1] + red[2] + red[3]) * (1.0f / 2048.0f) + 1e-6f);
  float v[8] = {a.x, a.y, a.z, a.w, b.x, b.y, b.z, b.w};
  int c0 = t * 8;
  u16* orow = out + (size_t)row * 2048 + c0;
#pragma unroll
  for (int j = 0; j < 8; ++j) orow[j] = f2bf(v[j] * rr * w[c0 + j]);
}

// ======================= gemm2: phase-pipelined GEMM =======================
// C[M][N] = A[M][K] @ Bt[N][K]^T. BM=128, BK=32, 256 thr (4 waves), 3 LDS
// slots, counted vmcnt, XOR-swizzled chunks. Merged single phase per K-tile:
// {ds_reads || 6 (4) stages -> vmcnt(LPT) -> barrier -> lgkmcnt(0) -> MFMA -> barrier}.
// All per-lane addressing hoisted to the prologue; K-loop unrolled x3 so the
// slot index is compile-time (folds into ds-offset immediates).
// BN=256: waves 1x4 (wave-tile 128x64); BN=128: waves 2x2 (wave-tile 64x64).
// EPI 1: C fp32 = acc + auxF32 ; EPI 4: v panels / gate ; EPI 5: q/k split ;
// EPI 6: interleaved gate/up -> silu(gate)*up.
template <int EPI, int BN, typename OutT>
__global__ __launch_bounds__(256, 2)
void gemm2(const u16* __restrict__ A, const u16* __restrict__ Bt,
           OutT* __restrict__ C, void* __restrict__ aux, float scale,
           int M, int N, int K, int gx) {
  constexpr int SB = (BN == 256) ? 24576 : 16384;  // slot bytes (A 8K + B BN*64)
  constexpr int NBS = (BN == 256) ? 4 : 2;         // B stage call sites
  constexpr int MB = (BN == 256) ? 8 : 4;          // A fragment count
  __shared__ char lds[3 * SB];
  int t = threadIdx.x, lane = t & 63, w = t >> 6;
  int c_ = lane & 15, r_ = lane >> 4;
  int wm = (BN == 256) ? 0 : (w >> 1);
  int wn = (BN == 256) ? w : (w & 1);

  // bijective XCD swizzle (grids here are multiples of 8)
  int nwg = gridDim.x;
  int wg = (blockIdx.x & 7) * (nwg >> 3) + (blockIdx.x >> 3);
  int gy = nwg / gx;
  int bx = wg / gy, by = wg % gy;
  int m0 = by * 128, n0 = bx * BN;

  // ---- hoisted per-lane staging base pointers ----
  const char* baseA[2];
#pragma unroll
  for (int h = 0; h < 2; ++h) {
    int p = h * 256 + t;
    int cc = p ^ ((p >> 3) & 7);
    baseA[h] = (const char*)A + ((size_t)(m0 + (cc >> 2)) * K + (cc & 3) * 8) * 2;
  }
  const char* baseB[NBS];
#pragma unroll
  for (int s = 0; s < NBS; ++s) {
    int p = s * 256 + t;
    int cc = p ^ ((p >> 3) & 7);
    baseB[s] = (const char*)Bt + ((size_t)(n0 + (cc >> 2)) * K + (cc & 3) * 8) * 2;
  }
  // ---- hoisted swizzled ds_read byte offsets ----
  int offA[MB], offB[4];
#pragma unroll
  for (int mb = 0; mb < MB; ++mb) {
    int cc = (wm * 64 + mb * 16 + c_) * 4 + r_;
    offA[mb] = (cc ^ ((cc >> 3) & 7)) * 16;
  }
#pragma unroll
  for (int nb = 0; nb < 4; ++nb) {
    int cc = (wn * 64 + nb * 16 + c_) * 4 + r_;
    offB[nb] = (cc ^ ((cc >> 3) & 7)) * 16 + 8192;
  }
  int ldsW = w * 1024;

  f4 z4 = {0.f, 0.f, 0.f, 0.f};
  f4 acc[MB][4];
#pragma unroll
  for (int mb = 0; mb < MB; ++mb)
#pragma unroll
    for (int nb = 0; nb < 4; ++nb) acc[mb][nb] = z4;

  int NT = K >> 5;

#define STAGE(S, ko)                                                        \
  {                                                                         \
    _Pragma("unroll") for (int h = 0; h < 2; ++h)                           \
        gload16(baseA[h] + (ko), lds + (S) * SB + h * 4096 + ldsW);         \
    _Pragma("unroll") for (int s = 0; s < NBS; ++s)                         \
        gload16(baseB[s] + (ko), lds + (S) * SB + 8192 + s * 4096 + ldsW);  \
  }
#define WAIT_VM()                                                           \
  if (BN == 256) { asm volatile("s_waitcnt vmcnt(6)" ::: "memory"); }       \
  else { asm volatile("s_waitcnt vmcnt(4)" ::: "memory"); }
#define KTILE(S)                                                            \
  {                                                                         \
    bh8 afr[MB], bfr[4];                                                    \
    _Pragma("unroll") for (int nb = 0; nb < 4; ++nb)                        \
        bfr[nb] = *(const bh8*)(lds + (S) * SB + offB[nb]);                 \
    _Pragma("unroll") for (int mb = 0; mb < MB; ++mb)                       \
        afr[mb] = *(const bh8*)(lds + (S) * SB + offA[mb]);                 \
    int kts = kt + 2; if (kts >= NT) kts -= NT;                             \
    STAGE(((S) + 2) % 3, kts << 6);                                         \
    WAIT_VM();                                                              \
    __builtin_amdgcn_s_barrier();                                           \
    asm volatile("s_waitcnt lgkmcnt(0)" ::: "memory");                      \
    __builtin_amdgcn_sched_barrier(0);                                      \
    __builtin_amdgcn_s_setprio(1);                                          \
    _Pragma("unroll") for (int mb = 0; mb < MB; ++mb)                       \
        _Pragma("unroll") for (int nb = 0; nb < 4; ++nb)                    \
            acc[mb][nb] = mfma16(afr[mb], bfr[nb], acc[mb][nb]);            \
    __builtin_amdgcn_s_setprio(0);                                          \
    __builtin_amdgcn_sched_barrier(0);                                      \
    __builtin_amdgcn_s_barrier();                                           \
    asm volatile("" ::: "memory");                                          \
  }

  // prologue: stage tiles 0 and 1
  STAGE(0, 0);
  STAGE(1, 64);
  WAIT_VM();  // tile 0 landed
  __builtin_amdgcn_s_barrier();
  asm volatile("" ::: "memory");

  int kt = 0;
  while (true) {
    KTILE(0); if (++kt == NT) break;
    KTILE(1); if (++kt == NT) break;
    KTILE(2); if (++kt == NT) break;
  }
  asm volatile("s_waitcnt vmcnt(0)" ::: "memory");  // drain dummy stages
#undef KTILE
#undef WAIT_VM
#undef STAGE

  // ---- epilogue ----
  int rowBase = m0 + wm * 64;
#pragma unroll
  for (int mb = 0; mb < MB; ++mb) {
#pragma unroll
    for (int rr = 0; rr < 4; ++rr) {
      int row = rowBase + mb * 16 + r_ * 4 + rr;
#pragma unroll
      for (int nb = 0; nb < 4; ++nb) {
        int col = n0 + wn * 64 + nb * 16 + c_;
        float val = acc[mb][nb][rr];
        if (EPI == 1) {
          ((float*)C)[(size_t)row * N + col] = val + ((const float*)aux)[(size_t)row * N + col];
        } else if (EPI == 5) {
          if (col < 1024) ((u16*)C)[(size_t)row * 1024 + col] = f2bf(val * scale);
          else ((u16*)aux)[(size_t)row * 1024 + col - 1024] = f2bf(val);
        } else if (EPI == 4) {
          if (col < 2048) {
            int bb = row >> 11, t2 = row & 2047;
            int pan = ((bb << 5) + (t2 >> 6)) * 8 + (col >> 8);
            int ii = t2 & 63, vv = col & 255;
            *(u16*)((char*)C + (size_t)pan * 32768 + vv * 128 + ((ii * 2) ^ ((vv & 7) << 4)))
                = f2bf(val);
          } else {
            ((u16*)aux)[(size_t)row * 2048 + col - 2048] = f2bf(val);
          }
        } else if (EPI == 6) {
          float other = __shfl_xor(val, 1, 64);
          if (lane & 1) {
            float gv = other;
            ((u16*)C)[(size_t)row * 5504 + (col >> 1)] = f2bf(val * (gv / (1.f + expf(-gv))));
          }
        }
      }
    }
  }
}

// ---------------- low-rank gate path: g = log_sigmoid(h@w1@w2 + b)/16 ----------------
__global__ __launch_bounds__(256)
void lowrank_k(const u16* __restrict__ h, const float* __restrict__ w1,
               const float* __restrict__ w2, const float* __restrict__ bias,
               float* __restrict__ g) {
  int row = blockIdx.x, t = threadIdx.x, lane = t & 63, wave = t >> 6;
  const u16* hr = h + (size_t)row * 2048;
  bh8 hv = *(const bh8*)&hr[t * 8];
  float p[16];
#pragma unroll
  for (int j = 0; j < 16; ++j) p[j] = 0.f;
#pragma unroll
  for (int kk = 0; kk < 8; ++kk) {
    float f = bf2f((u16)hv[kk]);
    const float* wrow = w1 + (size_t)(t * 8 + kk) * 16;
#pragma unroll
    for (int j = 0; j < 16; ++j) p[j] += f * wrow[j];
  }
#pragma unroll
  for (int j = 0; j < 16; ++j)
#pragma unroll
    for (int s = 32; s > 0; s >>= 1) p[j] += __shfl_xor(p[j], s, 64);
  __shared__ float gl[4][16];
  if (lane == 0) {
#pragma unroll
    for (int j = 0; j < 16; ++j) gl[wave][j] = p[j];
  }
  __syncthreads();
  float glow[16];
#pragma unroll
  for (int j = 0; j < 16; ++j) glow[j] = gl[0][j] + gl[1][j] + gl[2][j] + gl[3][j];
  float* grow = g + (size_t)row * 1024;
#pragma unroll
  for (int nn = 0; nn < 4; ++nn) {
    int n = nn * 256 + t;
    float z = bias[n];
#pragma unroll
    for (int j = 0; j < 16; ++j) z += glow[j] * w2[j * 1024 + n];
    float ls = fminf(z, 0.f) - log1pf(expf(-fabsf(z)));
    grow[n] = ls * (1.0f / 16.0f);
  }
}

// ---------------- gating prep (parallel over B*nc*H = 512 blocks) ----------------
__global__ __launch_bounds__(128)
void gprep_k(u16* __restrict__ q, u16* __restrict__ k, const float* __restrict__ g,
             u16* __restrict__ keT, float* __restrict__ ebl) {
  int bid = blockIdx.x;            // ((b*32+c)*8+h)
  int h = bid & 7, bc = bid >> 3;
  int b = bc >> 5, c = bc & 31;
  int ch = threadIdx.x;            // 0..127
  size_t base = ((size_t)(b * 2048 + c * 64)) * 1024 + h * 128 + ch;
  char* keTp = (char*)keT + (size_t)bid * 16384 + ch * 128;
  int sw = (ch & 7) << 4;
  float bacc = 0.f;
  for (int i8 = 0; i8 < 8; ++i8) {
    u16 kp[8];
#pragma unroll
    for (int e = 0; e < 8; ++e) {
      size_t off = base + (size_t)(i8 * 8 + e) * 1024;
      bacc += g[off];
      float eb = __expf(bacc);
      float reb = __builtin_amdgcn_rcpf(eb);
      float qv = bf2f(q[off]), kv = bf2f(k[off]);
      q[off] = f2bf(qv * eb);
      u16 kev = f2bf(kv * reb);
      k[off] = kev;
      kp[e] = kev;
    }
    *(bh8*)(keTp + ((i8 * 16) ^ sw)) = *(const bh8*)kp;
  }
  ebl[(size_t)bid * 128 + ch] = __expf(bacc);
}

// ---------------- GLA chunked scan (inter + intra, MFMA only) ----------------
__global__ __launch_bounds__(256)
void gla_scan(const u16* __restrict__ qg, const u16* __restrict__ kg,
              const u16* __restrict__ keTg, const u16* __restrict__ vTg,
              const float* __restrict__ eblg, float* __restrict__ outp) {
  __shared__ u16 qeL[64 * 128];   // [i][ch] swizzled
  __shared__ u16 keL[64 * 128];   // [i][ch] swizzled
  __shared__ u16 kTL[128 * 64];   // [ch][i] swizzled (baked by gprep)
  __shared__ u16 vTL[64 * 64];    // [v][i]  swizzled (baked by V-GEMM)
  __shared__ u16 AL[64 * 64];     // [i][j]  swizzled
  __shared__ u16 SbL[64 * 128];   // S^T bf16 [v][ch] swizzled
  __shared__ float SfL[64][133];  // S^T fp32 master (padded)

  int t = threadIdx.x, lane = t & 63, w = t >> 6;
  int vb = blockIdx.x & 3, bh = blockIdx.x >> 2;
  int b = bh >> 3, h = bh & 7;
  int c_ = lane & 15, r_ = lane >> 4;
  f4 z4 = {0.f, 0.f, 0.f, 0.f};

  for (int i = t; i < 64 * 128; i += 256) SbL[i] = 0;
  for (int i = t; i < 64 * 133; i += 256) ((float*)SfL)[i] = 0.f;

  const char* qbase = (const char*)qg + (size_t)b * 2048 * 2048 + h * 256;
  const char* kbase = (const char*)kg + (size_t)b * 2048 * 2048 + h * 256;
  int rowoff = (t >> 4) * 2048 + (t & 15) * 16;
  int4 pq[4], pk[4], pkt[4], pvt[2];

#define LOADCH(cc)                                                              \
  {                                                                             \
    const char* qc = qbase + (size_t)(cc) * 64 * 2048;                          \
    const char* kc = kbase + (size_t)(cc) * 64 * 2048;                          \
    int panel_ = ((b * 32 + (cc)) * 8 + h);                                     \
    const char* ktc = (const char*)keTg + (size_t)panel_ * 16384;               \
    const char* vtc = (const char*)vTg + (size_t)panel_ * 32768 + vb * 8192;    \
    _Pragma("unroll")                                                           \
    for (int j = 0; j < 4; ++j) {                                               \
      pq[j] = *(const int4*)(qc + j * 16 * 2048 + rowoff);                      \
      pk[j] = *(const int4*)(kc + j * 16 * 2048 + rowoff);                      \
      pkt[j] = *(const int4*)(ktc + j * 4096 + t * 16);                         \
    }                                                                           \
    _Pragma("unroll")                                                           \
    for (int j = 0; j < 2; ++j) pvt[j] = *(const int4*)(vtc + j * 4096 + t * 16); \
  }

  LOADCH(0);
  for (int c = 0; c < 32; ++c) {
#pragma unroll
    for (int j = 0; j < 4; ++j) {
      int L = j * 4096 + t * 16;
      int d = (L & ~255) | ((L & 255) ^ (((L >> 8) & 7) << 4));
      *(int4*)((char*)qeL + d) = pq[j];
      *(int4*)((char*)keL + d) = pk[j];
      *(int4*)((char*)kTL + L) = pkt[j];
    }
#pragma unroll
    for (int j = 0; j < 2; ++j) *(int4*)((char*)vTL + j * 4096 + t * 16) = pvt[j];
    if (c < 31) LOADCH(c + 1);
    int panel = ((b * 32 + c) * 8 + h);
    float eblr[2][4];
#pragma unroll
    for (int kt = 0; kt < 2; ++kt)
#pragma unroll
      for (int r = 0; r < 4; ++r)
        eblr[kt][r] = eblg[(size_t)panel * 128 + w * 32 + kt * 16 + r_ * 4 + r];
    __syncthreads();

    // phase 2: A = tril(qe@ke^T)  and  accS = keT@v
    f4 accA[4] = {z4, z4, z4, z4};
    f4 accS[2][4] = {{z4, z4, z4, z4}, {z4, z4, z4, z4}};
#pragma unroll
    for (int ks = 0; ks < 4; ++ks) {
      bh8 a = rd8(qeL, w * 16 + c_, ks * 32 + r_ * 8, 256);
#pragma unroll
      for (int n = 0; n < 4; ++n)
        accA[n] = mfma16(a, rd8(keL, n * 16 + c_, ks * 32 + r_ * 8, 256), accA[n]);
    }
#pragma unroll
    for (int ks = 0; ks < 2; ++ks) {
      bh8 bf_[4];
#pragma unroll
      for (int n = 0; n < 4; ++n) bf_[n] = rd8(vTL, n * 16 + c_, ks * 32 + r_ * 8, 128);
#pragma unroll
      for (int kt = 0; kt < 2; ++kt) {
        bh8 a = rd8(kTL, w * 32 + kt * 16 + c_, ks * 32 + r_ * 8, 128);
#pragma unroll
        for (int n = 0; n < 4; ++n) accS[kt][n] = mfma16(a, bf_[n], accS[kt][n]);
      }
    }
#pragma unroll
    for (int n = 0; n < 4; ++n)
#pragma unroll
      for (int r = 0; r < 4; ++r) {
        int i = w * 16 + r_ * 4 + r, j = n * 16 + c_;
        *(u16*)((char*)AL + i * 128 + ((j * 2) ^ ((i & 7) << 4))) =
            (j <= i) ? f2bf(accA[n][r]) : (u16)0;
      }
    __syncthreads();

    // phase 3: o = qe@S^T' + A@v
    f4 acco[4] = {z4, z4, z4, z4};
#pragma unroll
    for (int ks = 0; ks < 4; ++ks) {
      bh8 a = rd8(qeL, w * 16 + c_, ks * 32 + r_ * 8, 256);
#pragma unroll
      for (int n = 0; n < 4; ++n)
        acco[n] = mfma16(a, rd8(SbL, n * 16 + c_, ks * 32 + r_ * 8, 256), acco[n]);
    }
#pragma unroll
    for (int ks = 0; ks < 2; ++ks) {
      bh8 a = rd8(AL, w * 16 + c_, ks * 32 + r_ * 8, 128);
#pragma unroll
      for (int n = 0; n < 4; ++n)
        acco[n] = mfma16(a, rd8(vTL, n * 16 + c_, ks * 32 + r_ * 8, 128), acco[n]);
    }
    {
      size_t obase = (size_t)(b * 2048 + c * 64 + w * 16 + r_ * 4) * 2048 + h * 256 + vb * 64;
#pragma unroll
      for (int n = 0; n < 4; ++n)
#pragma unroll
        for (int r = 0; r < 4; ++r)
          outp[obase + (size_t)r * 2048 + n * 16 + c_] = acco[n][r];
    }
    __syncthreads();

    // phase 4: S = ebl * (S + accS)
#pragma unroll
    for (int kt = 0; kt < 2; ++kt)
#pragma unroll
      for (int n = 0; n < 4; ++n)
#pragma unroll
        for (int r = 0; r < 4; ++r) {
          int kk = w * 32 + kt * 16 + r_ * 4 + r;
          int vcol = n * 16 + c_;
          float nv = eblr[kt][r] * (SfL[vcol][kk] + accS[kt][n][r]);
          SfL[vcol][kk] = nv;
          *(u16*)((char*)SbL + vcol * 256 + ((kk * 2) ^ ((vcol & 7) << 4))) = f2bf(nv);
        }
    __syncthreads();
  }
#undef LOADCH
}

// ---------------- per-head RMSNorm * swish(gate) ----------------
__global__ __launch_bounds__(256)
void ogate_k(const float* __restrict__ o, const u16* __restrict__ gate,
             const float* __restrict__ gw, u16* __restrict__ og) {
  int tok = blockIdx.x, t = threadIdx.x;
  int head = t >> 5, l32 = t & 31, v0 = l32 * 8;
  size_t base = (size_t)tok * 2048 + head * 256 + v0;
  float4 a = *(const float4*)&o[base];
  float4 b = *(const float4*)&o[base + 4];
  float ov[8] = {a.x, a.y, a.z, a.w, b.x, b.y, b.z, b.w};
  float ss = 0.f;
#pragma unroll
  for (int j = 0; j < 8; ++j) ss += ov[j] * ov[j];
#pragma unroll
  for (int s = 16; s > 0; s >>= 1) ss += __shfl_xor(ss, s, 32);
  float rr = rsqrtf(ss * (1.0f / 256.0f) + 1e-6f);
#pragma unroll
  for (int j = 0; j < 8; ++j) {
    float gv = bf2f(gate[base + j]);
    float val = ov[j] * rr * gw[v0 + j];
    og[base + j] = f2bf(val * gv / (1.f + expf(-gv)));
  }
}

// ---------------- launch ----------------
extern "C" void kernel_launch(void* const* d_in, const int* in_sizes, int n_in,
                              void* d_out, int out_size, void* d_ws, size_t ws_size,
                              hipStream_t stream) {
  (void)in_sizes; (void)n_in; (void)out_size; (void)ws_size;
  const float* x = (const float*)d_in[0];
  const float* n1w = (const float*)d_in[1];
  const float* wq = (const float*)d_in[2];
  const float* wk = (const float*)d_in[3];
  const float* wv = (const float*)d_in[4];
  const float* gw1 = (const float*)d_in[5];
  const float* gw2 = (const float*)d_in[6];
  const float* gb = (const float*)d_in[7];
  const float* wg = (const float*)d_in[8];
  const float* gnw = (const float*)d_in[9];
  const float* wo = (const float*)d_in[10];
  const float* fnw = (const float*)d_in[11];
  const float* wgate = (const float*)d_in[12];
  const float* wup = (const float*)d_in[13];
  const float* wdown = (const float*)d_in[14];
  float* out = (float*)d_out;

  char* ws = (char*)d_ws;
  size_t off = 0;
  auto alloc = [&](size_t bytes) { size_t p = off; off += (bytes + 255) & ~(size_t)255; return p; };
  u16* wqT = (u16*)(ws + alloc(2ull * 1024 * 2048));   // [contiguous with wkT -> qk Bt]
  u16* wkT = (u16*)(ws + alloc(2ull * 1024 * 2048));
  u16* wvT = (u16*)(ws + alloc(2ull * 2048 * 2048));   // [contiguous with wgT -> vg Bt]
  u16* wgT = (u16*)(ws + alloc(2ull * 2048 * 2048));
  u16* woT = (u16*)(ws + alloc(2ull * 2048 * 2048));
  u16* btGU = (u16*)(ws + alloc(2ull * 11008 * 2048)); // interleaved gate/up
  u16* wdT = (u16*)(ws + alloc(2ull * 2048 * 5504));
  u16* h_bf = (u16*)(ws + alloc(2ull * 4096 * 2048));  // h -> keT panels -> og
  u16* q_bf = (u16*)(ws + alloc(2ull * 4096 * 1024));  // q -> qe (in place) -> h2
  u16* k_bf = (u16*)(ws + alloc(2ull * 4096 * 1024));  // k -> ke (in place)
  u16* vT_g = (u16*)(ws + alloc(2ull * 4096 * 2048));  // v panels [512][256][64] swizzled
  u16* gate_bf = (u16*)(ws + alloc(2ull * 4096 * 2048));
  float* g_f = (float*)(ws + alloc(4ull * 4096 * 1024));
  float* o_f = (float*)(ws + alloc(4ull * 4096 * 2048));  // later reused as x2
  u16* mid = (u16*)(ws + alloc(2ull * 4096 * 5504));
  float* ebl_g = (float*)(ws + alloc(4ull * 512 * 128));
  u16* keT_g = h_bf;
  u16* og = h_bf;
  u16* h2 = q_bf;
  float* x2 = o_f;

  dim3 blk(256);
  wtrans_k<<<dim3(32, 64), blk, 0, stream>>>(wq, wqT, 2048, 1024, 1, 0);
  wtrans_k<<<dim3(32, 64), blk, 0, stream>>>(wk, wkT, 2048, 1024, 1, 0);
  wtrans_k<<<dim3(64, 64), blk, 0, stream>>>(wv, wvT, 2048, 2048, 1, 0);
  wtrans_k<<<dim3(64, 64), blk, 0, stream>>>(wg, wgT, 2048, 2048, 1, 0);
  wtrans_k<<<dim3(64, 64), blk, 0, stream>>>(wo, woT, 2048, 2048, 1, 0);
  wtrans_k<<<dim3(172, 64), blk, 0, stream>>>(wgate, btGU, 2048, 5504, 2, 0);
  wtrans_k<<<dim3(172, 64), blk, 0, stream>>>(wup, btGU, 2048, 5504, 2, 1);
  wtrans_k<<<dim3(64, 172), blk, 0, stream>>>(wdown, wdT, 5504, 2048, 1, 0);

  rmsnorm_k<<<4096, blk, 0, stream>>>(x, n1w, h_bf);

  // q+k fused (Bt = wqT|wkT contiguous, BN=128), v+gate fused (BN=256)
  gemm2<5, 128, u16><<<512, blk, 0, stream>>>(h_bf, wqT, q_bf, k_bf, 0.08838834764831845f,
                                              4096, 2048, 2048, 16);
  gemm2<4, 256, u16><<<512, blk, 0, stream>>>(h_bf, wvT, vT_g, gate_bf, 1.f,
                                              4096, 4096, 2048, 16);
  lowrank_k<<<4096, blk, 0, stream>>>(h_bf, gw1, gw2, gb, g_f);

  // h_bf dead from here; reuse as keT panels
  gprep_k<<<512, dim3(128), 0, stream>>>(q_bf, k_bf, g_f, keT_g, ebl_g);

  gla_scan<<<64, blk, 0, stream>>>(q_bf, k_bf, keT_g, vT_g, ebl_g, o_f);

  ogate_k<<<4096, blk, 0, stream>>>(o_f, gate_bf, gnw, og);

  gemm2<1, 128, float><<<512, blk, 0, stream>>>(og, woT, x2, (void*)x, 1.f,
                                                4096, 2048, 2048, 16);

  rmsnorm_k<<<4096, blk, 0, stream>>>(x2, fnw, h2);

  gemm2<6, 256, u16><<<1376, blk, 0, stream>>>(h2, btGU, mid, nullptr, 1.f,
                                               4096, 11008, 2048, 43);
  gemm2<1, 128, float><<<512, blk, 0, stream>>>(mid, wdT, out, x2, 1.f,
                                                4096, 2048, 5504, 16);
}